// Round 2
// baseline (13191.879 us; speedup 1.0000x reference)
//
#include <hip/hip_runtime.h>

#define NN 100000
#define NE 400000
#define NB 4096
#define FN 78
#define FE 11
#define GD 256
#define NL 2
#define NT 2

typedef unsigned short u16;

__device__ __forceinline__ float lrelu_(float x){ return x > 0.f ? x : 0.01f*x; }
__device__ __forceinline__ float elu_(float x){ return x > 0.f ? x : expf(x) - 1.f; }
__device__ __forceinline__ float sigm_(float x){ return 1.f/(1.f + expf(-x)); }
__device__ __forceinline__ float dot4_(float4 a, float4 b){ return a.x*b.x + a.y*b.y + a.z*b.z + a.w*b.w; }

__device__ __forceinline__ float bf2f(u16 u){ return __uint_as_float(((unsigned)u) << 16); }
__device__ __forceinline__ u16 f2bf(float f){
  unsigned u = __float_as_uint(f);
  unsigned r = (u + 0x7fffu + ((u >> 16) & 1u)) >> 16;   // RNE
  return (u16)r;
}
__device__ __forceinline__ float ldv(const float* p, size_t i){ return p[i]; }
__device__ __forceinline__ float ldv(const u16* p, size_t i){ return bf2f(p[i]); }
__device__ __forceinline__ void stv(float* p, size_t i, float v){ p[i] = v; }
__device__ __forceinline__ void stv(u16* p, size_t i, float v){ p[i] = f2bf(v); }

// order-preserving float<->uint for atomicMax; 0 acts as -inf sentinel
__device__ __forceinline__ unsigned fenc_(float f){
  unsigned u = __float_as_uint(f);
  return (u & 0x80000000u) ? ~u : (u | 0x80000000u);
}
__device__ __forceinline__ float fdec_(unsigned u){
  return __uint_as_float((u & 0x80000000u) ? (u & 0x7fffffffu) : ~u);
}

__global__ void k_zero(float* p, size_t n){
  size_t i = (size_t)blockIdx.x*blockDim.x + threadIdx.x;
  size_t st = (size_t)gridDim.x*blockDim.x;
  for (; i < n; i += st) p[i] = 0.f;
}

// Y[r][j] = act( sum_{k<78} X[r][k]*W[j*ldw+k] + b[j] )  -> bf16 out
template<int TN>
__global__ void k_node_proj(const float* __restrict__ nf, const float* __restrict__ W, int ldw,
                            const float* __restrict__ b, int act, u16* __restrict__ outb, int N){
  __shared__ float sx[TN][FN];
  int base = blockIdx.x*TN, tid = threadIdx.x;
  for (int i = tid; i < TN*FN; i += 256){
    int n = i / FN, k = i % FN;
    int row = base + n;
    sx[n][k] = (row < N) ? nf[(size_t)row*FN + k] : 0.f;
  }
  __syncthreads();
  int j = tid;
  float acc[TN];
  #pragma unroll
  for (int n=0;n<TN;n++) acc[n]=0.f;
  for (int k=0;k<FN;k++){
    float w = W[(size_t)j*ldw + k];
    #pragma unroll
    for (int n=0;n<TN;n++) acc[n] += w*sx[n][k];
  }
  float bb = b ? b[j] : 0.f;
  #pragma unroll
  for (int n=0;n<TN;n++){
    int row = base + n;
    if (row < N){
      float v = acc[n] + bb;
      outb[(size_t)row*GD + j] = f2bf(act ? lrelu_(v) : v);
    }
  }
}

// GetContext logits: lrelu( W[0:256].hv[dst] + W[256:512].he1(e) + b ), he1 on the fly
__global__ void k_logits_ctx(const u16* __restrict__ hv, const int* __restrict__ dst,
                             const u16* __restrict__ P, const int* __restrict__ src,
                             const float* __restrict__ ef, const float* __restrict__ Wpe1,
                             const float* __restrict__ bpe1, const float* __restrict__ Wpe2,
                             const float* __restrict__ bpe2, float* __restrict__ logit, int E){
  int wv = threadIdx.x >> 6, lane = threadIdx.x & 63;
  int e = blockIdx.x*4 + wv;
  if (e >= E) return;
  int d = dst[e], s = src[e];
  int c0 = lane*4;
  ushort4 hv4 = *(const ushort4*)&hv[(size_t)d*GD + c0];
  ushort4 p4  = *(const ushort4*)&P[(size_t)s*GD + c0];
  float4 wa = *(const float4*)&Wpe2[c0];
  float4 wb = *(const float4*)&Wpe2[GD + c0];
  float efv[FE];
  #pragma unroll
  for (int k=0;k<FE;k++) efv[k] = ef[(size_t)e*FE + k];
  float acc = bf2f(hv4.x)*wa.x + bf2f(hv4.y)*wa.y + bf2f(hv4.z)*wa.z + bf2f(hv4.w)*wa.w;
  float pv[4] = {bf2f(p4.x), bf2f(p4.y), bf2f(p4.z), bf2f(p4.w)};
  float wbv[4] = {wb.x, wb.y, wb.z, wb.w};
  #pragma unroll
  for (int q=0;q<4;q++){
    int c = c0 + q;
    float t = pv[q] + bpe1[c];
    const float* wr = &Wpe1[(size_t)c*(FN+FE) + FN];
    #pragma unroll
    for (int k=0;k<FE;k++) t += wr[k]*efv[k];
    acc += lrelu_(t)*wbv[q];
  }
  #pragma unroll
  for (int off=32; off; off>>=1) acc += __shfl_down(acc, off);
  if (lane == 0) logit[e] = lrelu_(acc + bpe2[0]);
}

// GNN logits: lrelu( W[0:256].h[dst] + W[256:512].h[src] + b )
__global__ void k_logits_gnn(const u16* __restrict__ h, const int* __restrict__ dst,
                             const int* __restrict__ src, const float* __restrict__ W,
                             const float* __restrict__ bias, float* __restrict__ logit, int E){
  int wv = threadIdx.x >> 6, lane = threadIdx.x & 63;
  int e = blockIdx.x*4 + wv;
  if (e >= E) return;
  int d = dst[e], s = src[e];
  int c0 = lane*4;
  ushort4 hd = *(const ushort4*)&h[(size_t)d*GD + c0];
  ushort4 hs = *(const ushort4*)&h[(size_t)s*GD + c0];
  float4 wa = *(const float4*)&W[c0];
  float4 wb = *(const float4*)&W[GD + c0];
  float acc = bf2f(hd.x)*wa.x + bf2f(hd.y)*wa.y + bf2f(hd.z)*wa.z + bf2f(hd.w)*wa.w
            + bf2f(hs.x)*wb.x + bf2f(hs.y)*wb.y + bf2f(hs.z)*wb.z + bf2f(hs.w)*wb.w;
  #pragma unroll
  for (int off=32; off; off>>=1) acc += __shfl_down(acc, off);
  if (lane == 0) logit[e] = lrelu_(acc + bias[0]);
}

// Readout logits: lrelu( W[0:256].relu(g[ng[i]]) + W[256:512].h[i] + b )
__global__ void k_logits_ro(const float* __restrict__ g, const int* __restrict__ ng,
                            const u16* __restrict__ h, const float* __restrict__ W,
                            const float* __restrict__ bias, float* __restrict__ logit, int N){
  int wv = threadIdx.x >> 6, lane = threadIdx.x & 63;
  int i = blockIdx.x*4 + wv;
  if (i >= N) return;
  int gidx = ng[i];
  int c0 = lane*4;
  float4 gv = *(const float4*)&g[(size_t)gidx*GD + c0];
  ushort4 hv = *(const ushort4*)&h[(size_t)i*GD + c0];
  float4 wa = *(const float4*)&W[c0];
  float4 wb = *(const float4*)&W[GD + c0];
  float acc = fmaxf(gv.x,0.f)*wa.x + fmaxf(gv.y,0.f)*wa.y + fmaxf(gv.z,0.f)*wa.z + fmaxf(gv.w,0.f)*wa.w
            + bf2f(hv.x)*wb.x + bf2f(hv.y)*wb.y + bf2f(hv.z)*wb.z + bf2f(hv.w)*wb.w;
  #pragma unroll
  for (int off=32; off; off>>=1) acc += __shfl_down(acc, off);
  if (lane == 0) logit[i] = lrelu_(acc + bias[0]);
}

__global__ void k_segmax(const float* __restrict__ vals, const int* __restrict__ seg, int count,
                         unsigned* __restrict__ menc){
  int i = blockIdx.x*256 + threadIdx.x;
  if (i < count) atomicMax(&menc[seg[i]], fenc_(vals[i]));
}

__global__ void k_expsum(const float* __restrict__ vals, const int* __restrict__ seg, int count,
                         const unsigned* __restrict__ menc, float* __restrict__ eexp, float* __restrict__ s){
  int i = blockIdx.x*256 + threadIdx.x;
  if (i < count){
    float m = fdec_(menc[seg[i]]);
    float ev = expf(vals[i] - m);
    eexp[i] = ev;
    atomicAdd(&s[seg[i]], ev);
  }
}

// c[dst[e]][:] += a_e * (he1(e) @ W_et^T + b_et), he1 recomputed on the fly into LDS
template<int TN>
__global__ void __launch_bounds__(256)
k_et_fly(const u16* __restrict__ P, const int* __restrict__ src, const int* __restrict__ dst,
         const float* __restrict__ ef, const float* __restrict__ Wpe1, const float* __restrict__ bpe1,
         const float* __restrict__ eexp, const float* __restrict__ sden,
         const float* __restrict__ Wet, const float* __restrict__ bet, float* cb, int E){
  __shared__ float sx[TN][GD];
  __shared__ float sef[TN][FE];
  __shared__ float coef[TN];
  __shared__ int sd[TN], ss[TN];
  int base = blockIdx.x*TN, tid = threadIdx.x;
  for (int i = tid; i < TN*FE; i += 256){
    int n = i / FE, k = i % FE;
    int e = base + n;
    sef[n][k] = (e < E) ? ef[(size_t)e*FE + k] : 0.f;
  }
  if (tid < TN){
    int e = base + tid;
    if (e < E){ int d = dst[e]; sd[tid] = d; ss[tid] = src[e]; coef[tid] = eexp[e]/sden[d]; }
    else { sd[tid] = -1; ss[tid] = 0; coef[tid] = 0.f; }
  }
  __syncthreads();
  for (int i = tid; i < TN*GD; i += 256){
    int n = i >> 8, k = i & 255;
    float t = bf2f(P[(size_t)ss[n]*GD + k]) + bpe1[k];
    const float* wr = &Wpe1[(size_t)k*(FN+FE) + FN];
    #pragma unroll
    for (int kk=0;kk<FE;kk++) t += wr[kk]*sef[n][kk];
    sx[n][k] = lrelu_(t);
  }
  __syncthreads();
  int j = tid;
  float acc[TN];
  #pragma unroll
  for (int n=0;n<TN;n++) acc[n]=0.f;
  for (int k=0;k<GD;k+=4){
    float4 w = *(const float4*)&Wet[(size_t)j*GD + k];
    #pragma unroll
    for (int n=0;n<TN;n++){
      float4 x = *(const float4*)&sx[n][k];
      acc[n] += dot4_(w,x);
    }
  }
  float bj = bet[j];
  #pragma unroll
  for (int n=0;n<TN;n++){
    if (sd[n] >= 0) atomicAdd(&cb[(size_t)sd[n]*GD + j], coef[n]*(acc[n] + bj));
  }
}

// Y = X @ W^T + b, K=256, OUT=256, bf16 in/out
template<int TN>
__global__ void __launch_bounds__(256)
k_proj256(const u16* __restrict__ X, const float* __restrict__ W,
          const float* __restrict__ b, u16* __restrict__ Y, int R){
  __shared__ float sx[TN][GD];
  int base = blockIdx.x*TN, tid = threadIdx.x;
  for (int i = tid; i < TN*GD; i += 256){
    int n = i >> 8, k = i & 255;
    int r = base + n;
    sx[n][k] = (r < R) ? bf2f(X[(size_t)r*GD + k]) : 0.f;
  }
  __syncthreads();
  int j = tid;
  float acc[TN];
  #pragma unroll
  for (int n=0;n<TN;n++) acc[n]=0.f;
  for (int k=0;k<GD;k+=4){
    float4 w = *(const float4*)&W[(size_t)j*GD + k];
    #pragma unroll
    for (int n=0;n<TN;n++){
      float4 x = *(const float4*)&sx[n][k];
      acc[n] += dot4_(w,x);
    }
  }
  float bj = b[j];
  #pragma unroll
  for (int n=0;n<TN;n++){
    int r = base + n; if (r >= R) break;
    Y[(size_t)r*GD + j] = f2bf(acc[n] + bj);
  }
}

// out[seg[i]][:] += (eexp[i]/s[seg[i]]) * rows[ridx[i] or i][:]
__global__ void k_scatter_seg(const u16* __restrict__ rows, const int* __restrict__ ridx,
                              const int* __restrict__ seg, const float* __restrict__ eexp,
                              const float* __restrict__ sden, float* outb, int count){
  int base = blockIdx.x*8, j = threadIdx.x;
  #pragma unroll
  for (int n=0;n<8;n++){
    int i = base + n; if (i >= count) break;
    int d = seg[i];
    float coef = eexp[i]/sden[d];
    int r = ridx ? ridx[i] : i;
    atomicAdd(&outb[(size_t)d*GD + j], coef*bf2f(rows[(size_t)r*GD + j]));
  }
}

__global__ void k_segsum(const u16* __restrict__ h, const int* __restrict__ ng, float* g, int N){
  int base = blockIdx.x*8, j = threadIdx.x;
  #pragma unroll
  for (int n=0;n<8;n++){
    int i = base + n; if (i >= N) break;
    atomicAdd(&g[(size_t)ng[i]*GD + j], bf2f(h[(size_t)i*GD + j]));
  }
}

// hout[r] = relu(GRU(elu(x[r]), hprev[r]))
template<int TN, typename HT, typename OT>
__global__ void __launch_bounds__(256)
k_gru(const float* __restrict__ x, const HT* __restrict__ hprev,
      const float* __restrict__ Wih, const float* __restrict__ Whh,
      const float* __restrict__ bih, const float* __restrict__ bhh,
      OT* __restrict__ hout, int R){
  __shared__ float sx[TN][GD];
  __shared__ float sh[TN][GD];
  int base = blockIdx.x*TN, tid = threadIdx.x;
  for (int i = tid; i < TN*GD; i += 256){
    int n = i >> 8, k = i & 255;
    int r = base + n;
    float xv = (r < R) ? x[(size_t)r*GD + k] : 0.f;
    sx[n][k] = elu_(xv);
    sh[n][k] = (r < R) ? ldv(hprev, (size_t)r*GD + k) : 0.f;
  }
  __syncthreads();
  int j = tid;
  float gi0[TN], gi1[TN], gi2[TN], gh0[TN], gh1[TN], gh2[TN];
  #pragma unroll
  for (int n=0;n<TN;n++){ gi0[n]=0.f; gi1[n]=0.f; gi2[n]=0.f; gh0[n]=0.f; gh1[n]=0.f; gh2[n]=0.f; }
  const float* Wi0 = Wih + (size_t)j*GD;
  const float* Wi1 = Wih + (size_t)(j+GD)*GD;
  const float* Wi2 = Wih + (size_t)(j+2*GD)*GD;
  const float* Wh0 = Whh + (size_t)j*GD;
  const float* Wh1 = Whh + (size_t)(j+GD)*GD;
  const float* Wh2 = Whh + (size_t)(j+2*GD)*GD;
  for (int k=0;k<GD;k+=4){
    float4 wi0 = *(const float4*)&Wi0[k];
    float4 wi1 = *(const float4*)&Wi1[k];
    float4 wi2 = *(const float4*)&Wi2[k];
    float4 wh0 = *(const float4*)&Wh0[k];
    float4 wh1 = *(const float4*)&Wh1[k];
    float4 wh2 = *(const float4*)&Wh2[k];
    #pragma unroll
    for (int n=0;n<TN;n++){
      float4 xv = *(const float4*)&sx[n][k];
      float4 hv = *(const float4*)&sh[n][k];
      gi0[n] += dot4_(wi0,xv); gi1[n] += dot4_(wi1,xv); gi2[n] += dot4_(wi2,xv);
      gh0[n] += dot4_(wh0,hv); gh1[n] += dot4_(wh1,hv); gh2[n] += dot4_(wh2,hv);
    }
  }
  float bi0 = bih[j], bi1 = bih[j+GD], bi2 = bih[j+2*GD];
  float bh0 = bhh[j], bh1 = bhh[j+GD], bh2 = bhh[j+2*GD];
  #pragma unroll
  for (int n=0;n<TN;n++){
    int r = base + n; if (r >= R) break;
    float rr = sigm_(gi0[n] + bi0 + gh0[n] + bh0);
    float zz = sigm_(gi1[n] + bi1 + gh1[n] + bh1);
    float nn = tanhf(gi2[n] + bi2 + rr*(gh2[n] + bh2));
    float o = (1.f - zz)*nn + zz*sh[n][j];
    stv(hout, (size_t)r*GD + j, fmaxf(o, 0.f));
  }
}

__global__ void k_layernorm(const float* __restrict__ gb, const float* __restrict__ gamma,
                            const float* __restrict__ beta, float* __restrict__ outb){
  int r = blockIdx.x, j = threadIdx.x;
  float v = gb[(size_t)r*GD + j];
  float s1 = v, s2 = v*v;
  #pragma unroll
  for (int off=32; off; off>>=1){ s1 += __shfl_down(s1, off); s2 += __shfl_down(s2, off); }
  __shared__ float r1[4], r2[4];
  int wv = j >> 6, lane = j & 63;
  if (lane == 0){ r1[wv] = s1; r2[wv] = s2; }
  __syncthreads();
  float S1 = r1[0]+r1[1]+r1[2]+r1[3];
  float S2 = r2[0]+r2[1]+r2[2]+r2[3];
  float mu = S1/(float)GD;
  float var = fmaxf(S2/(float)GD - mu*mu, 0.f);
  outb[(size_t)r*GD + j] = (v - mu)/sqrtf(var + 1e-5f)*gamma[j] + beta[j];
}

extern "C" void kernel_launch(void* const* d_in, const int* in_sizes, int n_in,
                              void* d_out, int out_size, void* d_ws, size_t ws_size,
                              hipStream_t stream){
  const float* node_feats = (const float*)d_in[0];
  const float* edge_feats = (const float*)d_in[1];
  const int*   src        = (const int*)d_in[2];
  const int*   dst        = (const int*)d_in[3];
  const int*   node_graph = (const int*)d_in[4];
  const float* W_pn   = (const float*)d_in[5];
  const float* b_pn   = (const float*)d_in[6];
  const float* W_pe1  = (const float*)d_in[7];
  const float* b_pe1  = (const float*)d_in[8];
  const float* W_pe2  = (const float*)d_in[9];
  const float* b_pe2  = (const float*)d_in[10];
  const float* W_et   = (const float*)d_in[11];
  const float* b_et   = (const float*)d_in[12];
  const float* g0_Wih = (const float*)d_in[13];
  const float* g0_Whh = (const float*)d_in[14];
  const float* g0_bih = (const float*)d_in[15];
  const float* g0_bhh = (const float*)d_in[16];
  const float* gnn_W_pe = (const float*)d_in[17];
  const float* gnn_b_pe = (const float*)d_in[18];
  const float* gnn_W_pn = (const float*)d_in[19];
  const float* gnn_b_pn = (const float*)d_in[20];
  const float* gnn_Wih  = (const float*)d_in[21];
  const float* gnn_Whh  = (const float*)d_in[22];
  const float* gnn_bih  = (const float*)d_in[23];
  const float* gnn_bhh  = (const float*)d_in[24];
  const float* ro_W_cl = (const float*)d_in[25];
  const float* ro_b_cl = (const float*)d_in[26];
  const float* ro_W_pn = (const float*)d_in[27];
  const float* ro_b_pn = (const float*)d_in[28];
  const float* ro_Wih  = (const float*)d_in[29];
  const float* ro_Whh  = (const float*)d_in[30];
  const float* ro_bih  = (const float*)d_in[31];
  const float* ro_bhh  = (const float*)d_in[32];
  const float* ln_gamma = (const float*)d_in[33];
  const float* ln_beta  = (const float*)d_in[34];
  float* outp = (float*)d_out;

  // ---- workspace layout (bytes) ----
  char* w = (char*)d_ws;
  size_t need = 0;
  float*    cbuf  = (float*)(w + need); need += (size_t)NN*GD*4;   // 102.4 MB, f32 atomic target
  float*    gbuf  = (float*)(w + need); need += (size_t)NB*GD*4;
  float*    grbuf = (float*)(w + need); need += (size_t)NB*GD*4;
  float*    logit = (float*)(w + need); need += (size_t)NE*4;
  float*    eexp  = (float*)(w + need); need += (size_t)NE*4;
  unsigned* menc  = (unsigned*)(w + need); need += (size_t)NN*4;
  float*    sden  = (float*)(w + need); need += (size_t)NN*4;
  u16*      hbuf  = (u16*)(w + need); need += (size_t)NN*GD*2;     // 51.2 MB
  u16*      htmp  = (u16*)(w + need); need += (size_t)NN*GD*2;     // 51.2 MB
  if (ws_size < need) return;   // clean fail (poisoned out) instead of OOB crash
  u16* Pbuf   = hbuf;   // alive only until k_et_fly; hbuf written by gru0 after
  u16* hv_new = htmp;   // alive until gru0; later reused as hvtmp
  u16* hvtmp  = htmp;

  const int ZG = 2048;
  // ---------------- GetContext ----------------
  k_node_proj<8><<<(NN+7)/8, 256, 0, stream>>>(node_feats, W_pn, FN, b_pn, 1, hv_new, NN);
  k_node_proj<8><<<(NN+7)/8, 256, 0, stream>>>(node_feats, W_pe1, FN+FE, nullptr, 0, Pbuf, NN);
  k_logits_ctx<<<(NE+3)/4, 256, 0, stream>>>(hv_new, dst, Pbuf, src, edge_feats,
                                             W_pe1, b_pe1, W_pe2, b_pe2, logit, NE);
  k_zero<<<64, 256, 0, stream>>>((float*)menc, (size_t)2*NN);   // menc+sden contiguous
  k_segmax<<<(NE+255)/256, 256, 0, stream>>>(logit, dst, NE, menc);
  k_expsum<<<(NE+255)/256, 256, 0, stream>>>(logit, dst, NE, menc, eexp, sden);
  k_zero<<<ZG, 256, 0, stream>>>(cbuf, (size_t)NN*GD);
  k_et_fly<16><<<(NE+15)/16, 256, 0, stream>>>(Pbuf, src, dst, edge_feats, W_pe1, b_pe1,
                                               eexp, sden, W_et, b_et, cbuf, NE);
  k_gru<16,u16,u16><<<(NN+15)/16, 256, 0, stream>>>(cbuf, hv_new, g0_Wih, g0_Whh,
                                                    g0_bih, g0_bhh, hbuf, NN);

  // ---------------- GNN layers ----------------
  for (int l=0; l<NL; l++){
    k_logits_gnn<<<(NE+3)/4, 256, 0, stream>>>(hbuf, dst, src,
                                               gnn_W_pe + (size_t)l*2*GD, gnn_b_pe + l, logit, NE);
    k_zero<<<64, 256, 0, stream>>>((float*)menc, (size_t)2*NN);
    k_segmax<<<(NE+255)/256, 256, 0, stream>>>(logit, dst, NE, menc);
    k_expsum<<<(NE+255)/256, 256, 0, stream>>>(logit, dst, NE, menc, eexp, sden);
    k_proj256<16><<<(NN+15)/16, 256, 0, stream>>>(hbuf, gnn_W_pn + (size_t)l*GD*GD,
                                                  gnn_b_pn + (size_t)l*GD, hvtmp, NN);
    k_zero<<<ZG, 256, 0, stream>>>(cbuf, (size_t)NN*GD);
    k_scatter_seg<<<(NE+7)/8, 256, 0, stream>>>(hvtmp, src, dst, eexp, sden, cbuf, NE);
    k_gru<16,u16,u16><<<(NN+15)/16, 256, 0, stream>>>(cbuf, hbuf,
                                gnn_Wih + (size_t)l*3*GD*GD, gnn_Whh + (size_t)l*3*GD*GD,
                                gnn_bih + (size_t)l*3*GD, gnn_bhh + (size_t)l*3*GD, hbuf, NN);
  }

  // ---------------- Readout ----------------
  k_zero<<<256, 256, 0, stream>>>(gbuf, (size_t)NB*GD);
  k_segsum<<<(NN+7)/8, 256, 0, stream>>>(hbuf, node_graph, gbuf, NN);
  for (int t=0; t<NT; t++){
    k_logits_ro<<<(NN+3)/4, 256, 0, stream>>>(gbuf, node_graph, hbuf,
                                              ro_W_cl + (size_t)t*2*GD, ro_b_cl + t, logit, NN);
    k_zero<<<64, 256, 0, stream>>>((float*)menc, (size_t)2*NN);
    k_segmax<<<(NN+255)/256, 256, 0, stream>>>(logit, node_graph, NN, menc);
    k_expsum<<<(NN+255)/256, 256, 0, stream>>>(logit, node_graph, NN, menc, eexp, sden);
    k_proj256<16><<<(NN+15)/16, 256, 0, stream>>>(hbuf, ro_W_pn + (size_t)t*GD*GD,
                                                  ro_b_pn + (size_t)t*GD, hvtmp, NN);
    k_zero<<<256, 256, 0, stream>>>(grbuf, (size_t)NB*GD);
    k_scatter_seg<<<(NN+7)/8, 256, 0, stream>>>(hvtmp, nullptr, node_graph, eexp, sden, grbuf, NN);
    k_gru<16,float,float><<<(NB+15)/16, 256, 0, stream>>>(grbuf, gbuf,
                                ro_Wih + (size_t)t*3*GD*GD, ro_Whh + (size_t)t*3*GD*GD,
                                ro_bih + (size_t)t*3*GD, ro_bhh + (size_t)t*3*GD, gbuf, NB);
  }
  k_layernorm<<<NB, 256, 0, stream>>>(gbuf, ln_gamma, ln_beta, outp);
}

// Round 5
// 3922.364 us; speedup vs baseline: 3.3632x; 3.3632x over previous
//
#include <hip/hip_runtime.h>

#define NN 100000
#define NE 400000
#define NB 4096
#define FN 78
#define FE 11
#define GD 256
#define NL 2
#define NT 2

typedef unsigned short u16;
typedef __attribute__((ext_vector_type(8))) short bf16x8;
typedef __attribute__((ext_vector_type(4))) float f32x4;

__device__ __forceinline__ float lrelu_(float x){ return x > 0.f ? x : 0.01f*x; }
__device__ __forceinline__ float elu_(float x){ return x > 0.f ? x : expf(x) - 1.f; }
__device__ __forceinline__ float sigm_(float x){ return 1.f/(1.f + expf(-x)); }

__device__ __forceinline__ float bf2f(u16 u){ return __uint_as_float(((unsigned)u) << 16); }
__device__ __forceinline__ u16 f2bf(float f){
  unsigned u = __float_as_uint(f);
  unsigned r = (u + 0x7fffu + ((u >> 16) & 1u)) >> 16;   // RNE
  return (u16)r;
}
__device__ __forceinline__ float ldv(const float* p, size_t i){ return p[i]; }
__device__ __forceinline__ float ldv(const u16* p, size_t i){ return bf2f(p[i]); }
__device__ __forceinline__ void stv(float* p, size_t i, float v){ p[i] = v; }
__device__ __forceinline__ void stv(u16* p, size_t i, float v){ p[i] = f2bf(v); }

__device__ __forceinline__ unsigned fenc_(float f){
  unsigned u = __float_as_uint(f);
  return (u & 0x80000000u) ? ~u : (u | 0x80000000u);
}
__device__ __forceinline__ float fdec_(unsigned u){
  return __uint_as_float((u & 0x80000000u) ? (u & 0x7fffffffu) : ~u);
}

__global__ void k_zero(float* p, size_t n){
  size_t i = (size_t)blockIdx.x*blockDim.x + threadIdx.x;
  size_t st = (size_t)gridDim.x*blockDim.x;
  for (; i < n; i += st) p[i] = 0.f;
}

// Pack W[OUT][K] f32 -> bf16 B-fragment order: Bp[((c*(K/32)+ks)*64+l)*8+j] = W[c*16+(l&15)][ks*32+(l>>4)*8+j]
__global__ void k_pack_b(const float* __restrict__ W, u16* __restrict__ Bp, int OUT, int K){
  int t = blockIdx.x*256 + threadIdx.x;
  if (t >= OUT*K) return;
  int j = t & 7;
  int l = (t >> 3) & 63;
  int rest = t >> 9;
  int nks = K >> 5;
  int ks = rest % nks, c = rest / nks;
  int col = c*16 + (l & 15);
  int k = ks*32 + (l >> 4)*8 + j;
  Bp[t] = f2bf(W[(size_t)col*K + k]);
}

// Y[r][j] = act( sum_{k<78} X[r][k]*W[j*ldw+k] + b[j] )  -> bf16 out
template<int TN>
__global__ void k_node_proj(const float* __restrict__ nf, const float* __restrict__ W, int ldw,
                            const float* __restrict__ b, int act, u16* __restrict__ outb, int N){
  __shared__ float sx[TN][FN];
  int base = blockIdx.x*TN, tid = threadIdx.x;
  for (int i = tid; i < TN*FN; i += 256){
    int n = i / FN, k = i % FN;
    int row = base + n;
    sx[n][k] = (row < N) ? nf[(size_t)row*FN + k] : 0.f;
  }
  __syncthreads();
  int j = tid;
  float acc[TN];
  #pragma unroll
  for (int n=0;n<TN;n++) acc[n]=0.f;
  for (int k=0;k<FN;k++){
    float w = W[(size_t)j*ldw + k];
    #pragma unroll
    for (int n=0;n<TN;n++) acc[n] += w*sx[n][k];
  }
  float bb = b ? b[j] : 0.f;
  #pragma unroll
  for (int n=0;n<TN;n++){
    int row = base + n;
    if (row < N){
      float v = acc[n] + bb;
      outb[(size_t)row*GD + j] = f2bf(act ? lrelu_(v) : v);
    }
  }
}

__global__ void k_logits_ctx(const u16* __restrict__ hv, const int* __restrict__ dst,
                             const u16* __restrict__ P, const int* __restrict__ src,
                             const float* __restrict__ ef, const float* __restrict__ Wpe1,
                             const float* __restrict__ bpe1, const float* __restrict__ Wpe2,
                             const float* __restrict__ bpe2, float* __restrict__ logit, int E){
  int wv = threadIdx.x >> 6, lane = threadIdx.x & 63;
  int e = blockIdx.x*4 + wv;
  if (e >= E) return;
  int d = dst[e], s = src[e];
  int c0 = lane*4;
  ushort4 hv4 = *(const ushort4*)&hv[(size_t)d*GD + c0];
  ushort4 p4  = *(const ushort4*)&P[(size_t)s*GD + c0];
  float4 wa = *(const float4*)&Wpe2[c0];
  float4 wb = *(const float4*)&Wpe2[GD + c0];
  float efv[FE];
  #pragma unroll
  for (int k=0;k<FE;k++) efv[k] = ef[(size_t)e*FE + k];
  float acc = bf2f(hv4.x)*wa.x + bf2f(hv4.y)*wa.y + bf2f(hv4.z)*wa.z + bf2f(hv4.w)*wa.w;
  float pv[4] = {bf2f(p4.x), bf2f(p4.y), bf2f(p4.z), bf2f(p4.w)};
  float wbv[4] = {wb.x, wb.y, wb.z, wb.w};
  #pragma unroll
  for (int q=0;q<4;q++){
    int c = c0 + q;
    float t = pv[q] + bpe1[c];
    const float* wr = &Wpe1[(size_t)c*(FN+FE) + FN];
    #pragma unroll
    for (int k=0;k<FE;k++) t += wr[k]*efv[k];
    acc += lrelu_(t)*wbv[q];
  }
  #pragma unroll
  for (int off=32; off; off>>=1) acc += __shfl_down(acc, off);
  if (lane == 0) logit[e] = lrelu_(acc + bpe2[0]);
}

__global__ void k_logits_gnn(const u16* __restrict__ h, const int* __restrict__ dst,
                             const int* __restrict__ src, const float* __restrict__ W,
                             const float* __restrict__ bias, float* __restrict__ logit, int E){
  int wv = threadIdx.x >> 6, lane = threadIdx.x & 63;
  int e = blockIdx.x*4 + wv;
  if (e >= E) return;
  int d = dst[e], s = src[e];
  int c0 = lane*4;
  ushort4 hd = *(const ushort4*)&h[(size_t)d*GD + c0];
  ushort4 hs = *(const ushort4*)&h[(size_t)s*GD + c0];
  float4 wa = *(const float4*)&W[c0];
  float4 wb = *(const float4*)&W[GD + c0];
  float acc = bf2f(hd.x)*wa.x + bf2f(hd.y)*wa.y + bf2f(hd.z)*wa.z + bf2f(hd.w)*wa.w
            + bf2f(hs.x)*wb.x + bf2f(hs.y)*wb.y + bf2f(hs.z)*wb.z + bf2f(hs.w)*wb.w;
  #pragma unroll
  for (int off=32; off; off>>=1) acc += __shfl_down(acc, off);
  if (lane == 0) logit[e] = lrelu_(acc + bias[0]);
}

__global__ void k_logits_ro(const float* __restrict__ g, const int* __restrict__ ng,
                            const u16* __restrict__ h, const float* __restrict__ W,
                            const float* __restrict__ bias, float* __restrict__ logit, int N){
  int wv = threadIdx.x >> 6, lane = threadIdx.x & 63;
  int i = blockIdx.x*4 + wv;
  if (i >= N) return;
  int gidx = ng[i];
  int c0 = lane*4;
  float4 gv = *(const float4*)&g[(size_t)gidx*GD + c0];
  ushort4 hv = *(const ushort4*)&h[(size_t)i*GD + c0];
  float4 wa = *(const float4*)&W[c0];
  float4 wb = *(const float4*)&W[GD + c0];
  float acc = fmaxf(gv.x,0.f)*wa.x + fmaxf(gv.y,0.f)*wa.y + fmaxf(gv.z,0.f)*wa.z + fmaxf(gv.w,0.f)*wa.w
            + bf2f(hv.x)*wb.x + bf2f(hv.y)*wb.y + bf2f(hv.z)*wb.z + bf2f(hv.w)*wb.w;
  #pragma unroll
  for (int off=32; off; off>>=1) acc += __shfl_down(acc, off);
  if (lane == 0) logit[i] = lrelu_(acc + bias[0]);
}

__global__ void k_segmax(const float* __restrict__ vals, const int* __restrict__ seg, int count,
                         unsigned* __restrict__ menc){
  int i = blockIdx.x*256 + threadIdx.x;
  if (i < count) atomicMax(&menc[seg[i]], fenc_(vals[i]));
}

__global__ void k_expsum(const float* __restrict__ vals, const int* __restrict__ seg, int count,
                         const unsigned* __restrict__ menc, float* __restrict__ eexp, float* __restrict__ s){
  int i = blockIdx.x*256 + threadIdx.x;
  if (i < count){
    float m = fdec_(menc[seg[i]]);
    float ev = expf(vals[i] - m);
    eexp[i] = ev;
    atomicAdd(&s[seg[i]], ev);
  }
}

// ---- MFMA GRU: hout[r] = relu(GRU(elu(x[r]), hprev[r])) ----
// block = 16 rows, 256 thr = 4 waves; wave w owns cols [64w,64w+64) of all 3 gates.
template<typename HT, typename OT>
__global__ void __launch_bounds__(256)
k_gru_mfma(const float* __restrict__ x, const HT* __restrict__ hprev,
           const u16* __restrict__ Wihp, const u16* __restrict__ Whhp,
           const float* __restrict__ bih, const float* __restrict__ bhh,
           OT* __restrict__ hout, int R){
  int tid = threadIdx.x;
  int wave = tid >> 6, lane = tid & 63;
  int m = lane & 15, kg = lane >> 4;
  int r0 = blockIdx.x*16;

  f32x4 agi[3][4], agh[3][4];
  #pragma unroll
  for (int g=0;g<3;g++)
    #pragma unroll
    for (int t=0;t<4;t++){ agi[g][t] = (f32x4)(0.f); agh[g][t] = (f32x4)(0.f); }

  const float* xrow = x + (size_t)(r0 + m)*GD;
  #pragma unroll
  for (int ks=0; ks<8; ks++){
    int koff = ks*32 + kg*8;
    // A-frag x (elu applied inline)
    float4 x0 = *(const float4*)&xrow[koff];
    float4 x1 = *(const float4*)&xrow[koff+4];
    bf16x8 ax;
    ax[0]=(short)f2bf(elu_(x0.x)); ax[1]=(short)f2bf(elu_(x0.y));
    ax[2]=(short)f2bf(elu_(x0.z)); ax[3]=(short)f2bf(elu_(x0.w));
    ax[4]=(short)f2bf(elu_(x1.x)); ax[5]=(short)f2bf(elu_(x1.y));
    ax[6]=(short)f2bf(elu_(x1.z)); ax[7]=(short)f2bf(elu_(x1.w));
    // A-frag h
    bf16x8 ah;
    if constexpr (sizeof(HT) == 2){
      ah = *(const bf16x8*)&hprev[(size_t)(r0 + m)*GD + koff];
    } else {
      const float* hr = (const float*)hprev + (size_t)(r0 + m)*GD + koff;
      float4 h0 = *(const float4*)hr;
      float4 h1 = *(const float4*)(hr+4);
      ah[0]=(short)f2bf(h0.x); ah[1]=(short)f2bf(h0.y); ah[2]=(short)f2bf(h0.z); ah[3]=(short)f2bf(h0.w);
      ah[4]=(short)f2bf(h1.x); ah[5]=(short)f2bf(h1.y); ah[6]=(short)f2bf(h1.z); ah[7]=(short)f2bf(h1.w);
    }
    #pragma unroll
    for (int g=0;g<3;g++){
      #pragma unroll
      for (int t=0;t<4;t++){
        int c = g*16 + wave*4 + t;
        bf16x8 bi = *(const bf16x8*)&Wihp[(size_t)((c*8 + ks)*64 + lane)*8];
        bf16x8 bh = *(const bf16x8*)&Whhp[(size_t)((c*8 + ks)*64 + lane)*8];
        agi[g][t] = __builtin_amdgcn_mfma_f32_16x16x32_bf16(ax, bi, agi[g][t], 0, 0, 0);
        agh[g][t] = __builtin_amdgcn_mfma_f32_16x16x32_bf16(ah, bh, agh[g][t], 0, 0, 0);
      }
    }
  }
  // gates + combine, fully in-register (C layout: col = m, row = kg*4 + i)
  #pragma unroll
  for (int t=0;t<4;t++){
    int col = wave*64 + t*16 + m;
    float bir = bih[col],     bhr = bhh[col];
    float biz = bih[col+GD],  bhz = bhh[col+GD];
    float bin = bih[col+2*GD],bhn = bhh[col+2*GD];
    #pragma unroll
    for (int i=0;i<4;i++){
      int row = r0 + kg*4 + i;
      float rr = sigm_(agi[0][t][i] + bir + agh[0][t][i] + bhr);
      float zz = sigm_(agi[1][t][i] + biz + agh[1][t][i] + bhz);
      float nn = tanhf(agi[2][t][i] + bin + rr*(agh[2][t][i] + bhn));
      float hp = ldv(hprev, (size_t)row*GD + col);
      float o = (1.f - zz)*nn + zz*hp;
      stv(hout, (size_t)row*GD + col, fmaxf(o, 0.f));
    }
  }
}

// ---- MFMA projection: Y = X @ W^T + b, X bf16 [R][256], Y bf16, 32 rows/block ----
__global__ void __launch_bounds__(256)
k_proj_mfma(const u16* __restrict__ X, const u16* __restrict__ Wp,
            const float* __restrict__ b, u16* __restrict__ Y, int R){
  int tid = threadIdx.x;
  int wave = tid >> 6, lane = tid & 63;
  int m = lane & 15, kg = lane >> 4;
  int r0 = blockIdx.x*32;
  f32x4 acc[2][4];
  #pragma unroll
  for (int rf=0;rf<2;rf++)
    #pragma unroll
    for (int t=0;t<4;t++) acc[rf][t] = (f32x4)(0.f);
  #pragma unroll
  for (int ks=0; ks<8; ks++){
    int koff = ks*32 + kg*8;
    bf16x8 a0 = *(const bf16x8*)&X[(size_t)(r0 + m)*GD + koff];
    bf16x8 a1 = *(const bf16x8*)&X[(size_t)(r0 + 16 + m)*GD + koff];
    #pragma unroll
    for (int t=0;t<4;t++){
      int c = wave*4 + t;
      bf16x8 bv = *(const bf16x8*)&Wp[(size_t)((c*8 + ks)*64 + lane)*8];
      acc[0][t] = __builtin_amdgcn_mfma_f32_16x16x32_bf16(a0, bv, acc[0][t], 0, 0, 0);
      acc[1][t] = __builtin_amdgcn_mfma_f32_16x16x32_bf16(a1, bv, acc[1][t], 0, 0, 0);
    }
  }
  #pragma unroll
  for (int t=0;t<4;t++){
    int col = wave*64 + t*16 + m;
    float bb = b[col];
    #pragma unroll
    for (int rf=0;rf<2;rf++){
      #pragma unroll
      for (int i=0;i<4;i++){
        int row = r0 + rf*16 + kg*4 + i;
        Y[(size_t)row*GD + col] = f2bf(acc[rf][t][i] + bb);
      }
    }
  }
}

// ---- MFMA edge-transform + scatter: c[dst[e]] += a_e*(he1(e)@W_et^T + b_et) ----
__global__ void __launch_bounds__(256)
k_et_mfma(const u16* __restrict__ P, const int* __restrict__ src, const int* __restrict__ dst,
          const float* __restrict__ ef, const float* __restrict__ Wpe1, const float* __restrict__ bpe1,
          const float* __restrict__ eexp, const float* __restrict__ sden,
          const u16* __restrict__ Wetp, const float* __restrict__ bet, float* cb, int E){
  __shared__ __align__(16) u16 she[16*264];
  __shared__ float sef[16][FE];
  __shared__ float coef[16];
  __shared__ int sd[16], ss[16];
  int tid = threadIdx.x;
  int base = blockIdx.x*16;
  for (int i = tid; i < 16*FE; i += 256){
    int n = i / FE, k = i % FE;
    sef[n][k] = ef[(size_t)(base + n)*FE + k];
  }
  if (tid < 16){
    int e = base + tid;
    int d = dst[e]; sd[tid] = d; ss[tid] = src[e]; coef[tid] = eexp[e]/sden[d];
  }
  __syncthreads();
  for (int i = tid; i < 16*GD; i += 256){
    int n = i >> 8, k = i & 255;
    float t = bf2f(P[(size_t)ss[n]*GD + k]) + bpe1[k];
    const float* wr = &Wpe1[(size_t)k*(FN+FE) + FN];
    #pragma unroll
    for (int kk=0;kk<FE;kk++) t += wr[kk]*sef[n][kk];
    she[n*264 + k] = f2bf(lrelu_(t));
  }
  __syncthreads();
  int wave = tid >> 6, lane = tid & 63;
  int m = lane & 15, kg = lane >> 4;
  f32x4 acc[4];
  #pragma unroll
  for (int t=0;t<4;t++) acc[t] = (f32x4)(0.f);
  #pragma unroll
  for (int ks=0; ks<8; ks++){
    bf16x8 a = *(const bf16x8*)&she[m*264 + ks*32 + kg*8];
    #pragma unroll
    for (int t=0;t<4;t++){
      int c = wave*4 + t;
      bf16x8 bv = *(const bf16x8*)&Wetp[(size_t)((c*8 + ks)*64 + lane)*8];
      acc[t] = __builtin_amdgcn_mfma_f32_16x16x32_bf16(a, bv, acc[t], 0, 0, 0);
    }
  }
  #pragma unroll
  for (int t=0;t<4;t++){
    int col = wave*64 + t*16 + m;
    float bb = bet[col];
    #pragma unroll
    for (int i=0;i<4;i++){
      int n = kg*4 + i;
      atomicAdd(&cb[(size_t)sd[n]*GD + col], coef[n]*(acc[t][i] + bb));
    }
  }
}

__global__ void k_scatter_seg(const u16* __restrict__ rows, const int* __restrict__ ridx,
                              const int* __restrict__ seg, const float* __restrict__ eexp,
                              const float* __restrict__ sden, float* outb, int count){
  int base = blockIdx.x*8, j = threadIdx.x;
  #pragma unroll
  for (int n=0;n<8;n++){
    int i = base + n; if (i >= count) break;
    int d = seg[i];
    float coef = eexp[i]/sden[d];
    int r = ridx ? ridx[i] : i;
    atomicAdd(&outb[(size_t)d*GD + j], coef*bf2f(rows[(size_t)r*GD + j]));
  }
}

__global__ void k_segsum(const u16* __restrict__ h, const int* __restrict__ ng, float* g, int N){
  int base = blockIdx.x*8, j = threadIdx.x;
  #pragma unroll
  for (int n=0;n<8;n++){
    int i = base + n; if (i >= N) break;
    atomicAdd(&g[(size_t)ng[i]*GD + j], bf2f(h[(size_t)i*GD + j]));
  }
}

__global__ void k_layernorm(const float* __restrict__ gb, const float* __restrict__ gamma,
                            const float* __restrict__ beta, float* __restrict__ outb){
  int r = blockIdx.x, j = threadIdx.x;
  float v = gb[(size_t)r*GD + j];
  float s1 = v, s2 = v*v;
  #pragma unroll
  for (int off=32; off; off>>=1){ s1 += __shfl_down(s1, off); s2 += __shfl_down(s2, off); }
  __shared__ float r1[4], r2[4];
  int wv = j >> 6, lane = j & 63;
  if (lane == 0){ r1[wv] = s1; r2[wv] = s2; }
  __syncthreads();
  float S1 = r1[0]+r1[1]+r1[2]+r1[3];
  float S2 = r2[0]+r2[1]+r2[2]+r2[3];
  float mu = S1/(float)GD;
  float var = fmaxf(S2/(float)GD - mu*mu, 0.f);
  outb[(size_t)r*GD + j] = (v - mu)/sqrtf(var + 1e-5f)*gamma[j] + beta[j];
}

extern "C" void kernel_launch(void* const* d_in, const int* in_sizes, int n_in,
                              void* d_out, int out_size, void* d_ws, size_t ws_size,
                              hipStream_t stream){
  const float* node_feats = (const float*)d_in[0];
  const float* edge_feats = (const float*)d_in[1];
  const int*   src        = (const int*)d_in[2];
  const int*   dst        = (const int*)d_in[3];
  const int*   node_graph = (const int*)d_in[4];
  const float* W_pn   = (const float*)d_in[5];
  const float* b_pn   = (const float*)d_in[6];
  const float* W_pe1  = (const float*)d_in[7];
  const float* b_pe1  = (const float*)d_in[8];
  const float* W_pe2  = (const float*)d_in[9];
  const float* b_pe2  = (const float*)d_in[10];
  const float* W_et   = (const float*)d_in[11];
  const float* b_et   = (const float*)d_in[12];
  const float* g0_Wih = (const float*)d_in[13];
  const float* g0_Whh = (const float*)d_in[14];
  const float* g0_bih = (const float*)d_in[15];
  const float* g0_bhh = (const float*)d_in[16];
  const float* gnn_W_pe = (const float*)d_in[17];
  const float* gnn_b_pe = (const float*)d_in[18];
  const float* gnn_W_pn = (const float*)d_in[19];
  const float* gnn_b_pn = (const float*)d_in[20];
  const float* gnn_Wih  = (const float*)d_in[21];
  const float* gnn_Whh  = (const float*)d_in[22];
  const float* gnn_bih  = (const float*)d_in[23];
  const float* gnn_bhh  = (const float*)d_in[24];
  const float* ro_W_cl = (const float*)d_in[25];
  const float* ro_b_cl = (const float*)d_in[26];
  const float* ro_W_pn = (const float*)d_in[27];
  const float* ro_b_pn = (const float*)d_in[28];
  const float* ro_Wih  = (const float*)d_in[29];
  const float* ro_Whh  = (const float*)d_in[30];
  const float* ro_bih  = (const float*)d_in[31];
  const float* ro_bhh  = (const float*)d_in[32];
  const float* ln_gamma = (const float*)d_in[33];
  const float* ln_beta  = (const float*)d_in[34];
  float* outp = (float*)d_out;

  // ---- workspace layout (bytes) ----
  char* w = (char*)d_ws;
  size_t need = 0;
  float*    cbuf  = (float*)(w + need); need += (size_t)NN*GD*4;
  float*    gbuf  = (float*)(w + need); need += (size_t)NB*GD*4;
  float*    grbuf = (float*)(w + need); need += (size_t)NB*GD*4;
  float*    logit = (float*)(w + need); need += (size_t)NE*4;
  float*    eexp  = (float*)(w + need); need += (size_t)NE*4;
  unsigned* menc  = (unsigned*)(w + need); need += (size_t)NN*4;
  float*    sden  = (float*)(w + need); need += (size_t)NN*4;
  u16*      hbuf  = (u16*)(w + need); need += (size_t)NN*GD*2;
  u16*      htmp  = (u16*)(w + need); need += (size_t)NN*GD*2;
  // packed bf16 weights (B-fragment order)
  u16* pGru = (u16*)(w + need); need += (size_t)10*768*GD*2;   // 5 layers x (Wih,Whh)
  u16* pPn  = (u16*)(w + need); need += (size_t)4*GD*GD*2;     // gnn_W_pn x2, ro_W_pn x2
  u16* pEt  = (u16*)(w + need); need += (size_t)GD*GD*2;
  if (ws_size < need) return;
  u16* Pbuf   = hbuf;
  u16* hv_new = htmp;
  u16* hvtmp  = htmp;

  const size_t GW = (size_t)768*GD;   // elems per packed GRU matrix
  const size_t PW = (size_t)GD*GD;

  // ---- weight packing (cheap, every launch, deterministic) ----
  k_pack_b<<<768, 256, 0, stream>>>(g0_Wih, pGru + 0*GW, 768, GD);
  k_pack_b<<<768, 256, 0, stream>>>(g0_Whh, pGru + 1*GW, 768, GD);
  for (int l=0;l<NL;l++){
    k_pack_b<<<768, 256, 0, stream>>>(gnn_Wih + (size_t)l*3*GD*GD, pGru + (2+2*l)*GW, 768, GD);
    k_pack_b<<<768, 256, 0, stream>>>(gnn_Whh + (size_t)l*3*GD*GD, pGru + (3+2*l)*GW, 768, GD);
    k_pack_b<<<256, 256, 0, stream>>>(gnn_W_pn + (size_t)l*GD*GD, pPn + l*PW, GD, GD);
  }
  for (int t=0;t<NT;t++){
    k_pack_b<<<768, 256, 0, stream>>>(ro_Wih + (size_t)t*3*GD*GD, pGru + (6+2*t)*GW, 768, GD);
    k_pack_b<<<768, 256, 0, stream>>>(ro_Whh + (size_t)t*3*GD*GD, pGru + (7+2*t)*GW, 768, GD);
    k_pack_b<<<256, 256, 0, stream>>>(ro_W_pn + (size_t)t*GD*GD, pPn + (2+t)*PW, GD, GD);
  }
  k_pack_b<<<256, 256, 0, stream>>>(W_et, pEt, GD, GD);

  const int ZG = 2048;
  // ---------------- GetContext ----------------
  k_node_proj<8><<<(NN+7)/8, 256, 0, stream>>>(node_feats, W_pn, FN, b_pn, 1, hv_new, NN);
  k_node_proj<8><<<(NN+7)/8, 256, 0, stream>>>(node_feats, W_pe1, FN+FE, nullptr, 0, Pbuf, NN);
  k_logits_ctx<<<(NE+3)/4, 256, 0, stream>>>(hv_new, dst, Pbuf, src, edge_feats,
                                             W_pe1, b_pe1, W_pe2, b_pe2, logit, NE);
  k_zero<<<64, 256, 0, stream>>>((float*)menc, (size_t)2*NN);
  k_segmax<<<(NE+255)/256, 256, 0, stream>>>(logit, dst, NE, menc);
  k_expsum<<<(NE+255)/256, 256, 0, stream>>>(logit, dst, NE, menc, eexp, sden);
  k_zero<<<ZG, 256, 0, stream>>>(cbuf, (size_t)NN*GD);
  k_et_mfma<<<NE/16, 256, 0, stream>>>(Pbuf, src, dst, edge_feats, W_pe1, b_pe1,
                                       eexp, sden, pEt, b_et, cbuf, NE);
  k_gru_mfma<u16,u16><<<NN/16, 256, 0, stream>>>(cbuf, hv_new, pGru + 0*GW, pGru + 1*GW,
                                                 g0_bih, g0_bhh, hbuf, NN);

  // ---------------- GNN layers ----------------
  for (int l=0; l<NL; l++){
    k_logits_gnn<<<(NE+3)/4, 256, 0, stream>>>(hbuf, dst, src,
                                               gnn_W_pe + (size_t)l*2*GD, gnn_b_pe + l, logit, NE);
    k_zero<<<64, 256, 0, stream>>>((float*)menc, (size_t)2*NN);
    k_segmax<<<(NE+255)/256, 256, 0, stream>>>(logit, dst, NE, menc);
    k_expsum<<<(NE+255)/256, 256, 0, stream>>>(logit, dst, NE, menc, eexp, sden);
    k_proj_mfma<<<NN/32, 256, 0, stream>>>(hbuf, pPn + l*PW, gnn_b_pn + (size_t)l*GD, hvtmp, NN);
    k_zero<<<ZG, 256, 0, stream>>>(cbuf, (size_t)NN*GD);
    k_scatter_seg<<<(NE+7)/8, 256, 0, stream>>>(hvtmp, src, dst, eexp, sden, cbuf, NE);
    k_gru_mfma<u16,u16><<<NN/16, 256, 0, stream>>>(cbuf, hbuf,
                                pGru + (2+2*l)*GW, pGru + (3+2*l)*GW,
                                gnn_bih + (size_t)l*3*GD, gnn_bhh + (size_t)l*3*GD, hbuf, NN);
  }

  // ---------------- Readout ----------------
  k_zero<<<256, 256, 0, stream>>>(gbuf, (size_t)NB*GD);
  k_segsum<<<(NN+7)/8, 256, 0, stream>>>(hbuf, node_graph, gbuf, NN);
  for (int t=0; t<NT; t++){
    k_logits_ro<<<(NN+3)/4, 256, 0, stream>>>(gbuf, node_graph, hbuf,
                                              ro_W_cl + (size_t)t*2*GD, ro_b_cl + t, logit, NN);
    k_zero<<<64, 256, 0, stream>>>((float*)menc, (size_t)2*NN);
    k_segmax<<<(NN+255)/256, 256, 0, stream>>>(logit, node_graph, NN, menc);
    k_expsum<<<(NN+255)/256, 256, 0, stream>>>(logit, node_graph, NN, menc, eexp, sden);
    k_proj_mfma<<<NN/32, 256, 0, stream>>>(hbuf, pPn + (2+t)*PW, ro_b_pn + (size_t)t*GD, hvtmp, NN);
    k_zero<<<256, 256, 0, stream>>>(grbuf, (size_t)NB*GD);
    k_scatter_seg<<<(NN+7)/8, 256, 0, stream>>>(hvtmp, nullptr, node_graph, eexp, sden, grbuf, NN);
    k_gru_mfma<float,float><<<NB/16, 256, 0, stream>>>(grbuf, gbuf,
                                pGru + (6+2*t)*GW, pGru + (7+2*t)*GW,
                                ro_bih + (size_t)t*3*GD, ro_bhh + (size_t)t*3*GD, gbuf, NB);
  }
  k_layernorm<<<NB, 256, 0, stream>>>(gbuf, ln_gamma, ln_beta, outp);
}

// Round 6
// 3673.355 us; speedup vs baseline: 3.5912x; 1.0678x over previous
//
#include <hip/hip_runtime.h>

#define NN 100000
#define NE 400000
#define NB 4096
#define FN 78
#define FE 11
#define GD 256
#define NL 2
#define NT 2

typedef unsigned short u16;
typedef __attribute__((ext_vector_type(8))) short bf16x8;
typedef __attribute__((ext_vector_type(4))) float f32x4;

__device__ __forceinline__ float lrelu_(float x){ return x > 0.f ? x : 0.01f*x; }
__device__ __forceinline__ float elu_(float x){ return x > 0.f ? x : expf(x) - 1.f; }
__device__ __forceinline__ float sigm_(float x){ return 1.f/(1.f + expf(-x)); }

__device__ __forceinline__ float bf2f(u16 u){ return __uint_as_float(((unsigned)u) << 16); }
__device__ __forceinline__ u16 f2bf(float f){
  unsigned u = __float_as_uint(f);
  unsigned r = (u + 0x7fffu + ((u >> 16) & 1u)) >> 16;   // RNE
  return (u16)r;
}
__device__ __forceinline__ float ldv(const float* p, size_t i){ return p[i]; }
__device__ __forceinline__ float ldv(const u16* p, size_t i){ return bf2f(p[i]); }
__device__ __forceinline__ void stv(float* p, size_t i, float v){ p[i] = v; }
__device__ __forceinline__ void stv(u16* p, size_t i, float v){ p[i] = f2bf(v); }

__device__ __forceinline__ unsigned fenc_(float f){
  unsigned u = __float_as_uint(f);
  return (u & 0x80000000u) ? ~u : (u | 0x80000000u);
}
__device__ __forceinline__ float fdec_(unsigned u){
  return __uint_as_float((u & 0x80000000u) ? (u & 0x7fffffffu) : ~u);
}

__global__ void k_zero(float* p, size_t n){
  size_t i = (size_t)blockIdx.x*blockDim.x + threadIdx.x;
  size_t st = (size_t)gridDim.x*blockDim.x;
  for (; i < n; i += st) p[i] = 0.f;
}

// Pack W[OUT][K] f32 -> bf16 B-fragment order
__global__ void k_pack_b(const float* __restrict__ W, u16* __restrict__ Bp, int OUT, int K){
  int t = blockIdx.x*256 + threadIdx.x;
  if (t >= OUT*K) return;
  int j = t & 7;
  int l = (t >> 3) & 63;
  int rest = t >> 9;
  int nks = K >> 5;
  int ks = rest % nks, c = rest / nks;
  int col = c*16 + (l & 15);
  int k = ks*32 + (l >> 4)*8 + j;
  Bp[t] = f2bf(W[(size_t)col*K + k]);
}

// Y[r][j] = act( sum_{k<78} X[r][k]*W[j*ldw+k] + b[j] )  -> bf16 out
template<int TN>
__global__ void k_node_proj(const float* __restrict__ nf, const float* __restrict__ W, int ldw,
                            const float* __restrict__ b, int act, u16* __restrict__ outb, int N){
  __shared__ float sx[TN][FN];
  int base = blockIdx.x*TN, tid = threadIdx.x;
  for (int i = tid; i < TN*FN; i += 256){
    int n = i / FN, k = i % FN;
    int row = base + n;
    sx[n][k] = (row < N) ? nf[(size_t)row*FN + k] : 0.f;
  }
  __syncthreads();
  int j = tid;
  float acc[TN];
  #pragma unroll
  for (int n=0;n<TN;n++) acc[n]=0.f;
  for (int k=0;k<FN;k++){
    float w = W[(size_t)j*ldw + k];
    #pragma unroll
    for (int n=0;n<TN;n++) acc[n] += w*sx[n][k];
  }
  float bb = b ? b[j] : 0.f;
  #pragma unroll
  for (int n=0;n<TN;n++){
    int row = base + n;
    if (row < N){
      float v = acc[n] + bb;
      outb[(size_t)row*GD + j] = f2bf(act ? lrelu_(v) : v);
    }
  }
}

// ---- per-node dot kernels (decomposed attention logits) ----
// za[i] = wv[0:256] . rows[i],  zb[i] = wv[256:512] . rows[i]
__global__ void k_dot2_bf16(const u16* __restrict__ rows, const float* __restrict__ wv,
                            float* __restrict__ za, float* __restrict__ zb, int N){
  int wav = threadIdx.x >> 6, lane = threadIdx.x & 63;
  int i = blockIdx.x*4 + wav;
  if (i >= N) return;
  int c0 = lane*4;
  ushort4 r4 = *(const ushort4*)&rows[(size_t)i*GD + c0];
  float4 wa = *(const float4*)&wv[c0];
  float4 wb = *(const float4*)&wv[GD + c0];
  float v0 = bf2f(r4.x), v1 = bf2f(r4.y), v2 = bf2f(r4.z), v3 = bf2f(r4.w);
  float va = v0*wa.x + v1*wa.y + v2*wa.z + v3*wa.w;
  float vb = v0*wb.x + v1*wb.y + v2*wb.z + v3*wb.w;
  #pragma unroll
  for (int off=32; off; off>>=1){ va += __shfl_down(va, off); vb += __shfl_down(vb, off); }
  if (lane == 0){ za[i] = va; zb[i] = vb; }
}

// z[i] = wv[0:256] . rows[i]
__global__ void k_dot1_bf16(const u16* __restrict__ rows, const float* __restrict__ wv,
                            float* __restrict__ z, int N){
  int wav = threadIdx.x >> 6, lane = threadIdx.x & 63;
  int i = blockIdx.x*4 + wav;
  if (i >= N) return;
  int c0 = lane*4;
  ushort4 r4 = *(const ushort4*)&rows[(size_t)i*GD + c0];
  float4 wa = *(const float4*)&wv[c0];
  float va = bf2f(r4.x)*wa.x + bf2f(r4.y)*wa.y + bf2f(r4.z)*wa.z + bf2f(r4.w)*wa.w;
  #pragma unroll
  for (int off=32; off; off>>=1) va += __shfl_down(va, off);
  if (lane == 0) z[i] = va;
}

// zg[b] = wv[0:256] . relu(g[b])   (g is f32)
__global__ void k_dotg_relu(const float* __restrict__ g, const float* __restrict__ wv,
                            float* __restrict__ zg, int B){
  int wav = threadIdx.x >> 6, lane = threadIdx.x & 63;
  int i = blockIdx.x*4 + wav;
  if (i >= B) return;
  int c0 = lane*4;
  float4 gv = *(const float4*)&g[(size_t)i*GD + c0];
  float4 wa = *(const float4*)&wv[c0];
  float va = fmaxf(gv.x,0.f)*wa.x + fmaxf(gv.y,0.f)*wa.y + fmaxf(gv.z,0.f)*wa.z + fmaxf(gv.w,0.f)*wa.w;
  #pragma unroll
  for (int off=32; off; off>>=1) va += __shfl_down(va, off);
  if (lane == 0) zg[i] = va;
}

// logit[e] = lrelu( za[dst[e]] + zb[src[e]] + bias )
__global__ void k_edge_logit(const float* __restrict__ za, const float* __restrict__ zb,
                             const int* __restrict__ dst, const int* __restrict__ src,
                             const float* __restrict__ bias, float* __restrict__ logit, int E){
  int e = blockIdx.x*256 + threadIdx.x;
  if (e < E) logit[e] = lrelu_(za[dst[e]] + zb[src[e]] + bias[0]);
}

// logit[i] = lrelu( zg[ng[i]] + zh[i] + bias )
__global__ void k_node_logit(const float* __restrict__ zg, const int* __restrict__ ng,
                             const float* __restrict__ zh, const float* __restrict__ bias,
                             float* __restrict__ logit, int N){
  int i = blockIdx.x*256 + threadIdx.x;
  if (i < N) logit[i] = lrelu_(zg[ng[i]] + zh[i] + bias[0]);
}

// ctx logits, decomposed hv-half: logit[e] = lrelu( za[dst[e]] + Wb.he1(e) + b )
__global__ void k_logits_ctx2(const float* __restrict__ za, const int* __restrict__ dst,
                              const u16* __restrict__ P, const int* __restrict__ src,
                              const float* __restrict__ ef, const float* __restrict__ Wpe1,
                              const float* __restrict__ bpe1, const float* __restrict__ Wpe2,
                              const float* __restrict__ bpe2, float* __restrict__ logit, int E){
  int wav = threadIdx.x >> 6, lane = threadIdx.x & 63;
  int e = blockIdx.x*4 + wav;
  if (e >= E) return;
  int s = src[e];
  int c0 = lane*4;
  ushort4 p4 = *(const ushort4*)&P[(size_t)s*GD + c0];
  float4 wb = *(const float4*)&Wpe2[GD + c0];
  float efv[FE];
  #pragma unroll
  for (int k=0;k<FE;k++) efv[k] = ef[(size_t)e*FE + k];
  float pv[4] = {bf2f(p4.x), bf2f(p4.y), bf2f(p4.z), bf2f(p4.w)};
  float wbv[4] = {wb.x, wb.y, wb.z, wb.w};
  float acc = 0.f;
  #pragma unroll
  for (int q=0;q<4;q++){
    int c = c0 + q;
    float t = pv[q] + bpe1[c];
    const float* wr = &Wpe1[(size_t)c*(FN+FE) + FN];
    #pragma unroll
    for (int k=0;k<FE;k++) t += wr[k]*efv[k];
    acc += lrelu_(t)*wbv[q];
  }
  #pragma unroll
  for (int off=32; off; off>>=1) acc += __shfl_down(acc, off);
  if (lane == 0) logit[e] = lrelu_(acc + za[dst[e]] + bpe2[0]);
}

__global__ void k_segmax(const float* __restrict__ vals, const int* __restrict__ seg, int count,
                         unsigned* __restrict__ menc){
  int i = blockIdx.x*256 + threadIdx.x;
  if (i < count) atomicMax(&menc[seg[i]], fenc_(vals[i]));
}

__global__ void k_expsum(const float* __restrict__ vals, const int* __restrict__ seg, int count,
                         const unsigned* __restrict__ menc, float* __restrict__ eexp, float* __restrict__ s){
  int i = blockIdx.x*256 + threadIdx.x;
  if (i < count){
    float m = fdec_(menc[seg[i]]);
    float ev = expf(vals[i] - m);
    eexp[i] = ev;
    atomicAdd(&s[seg[i]], ev);
  }
}

// ---- MFMA GRU ----
template<typename HT, typename OT>
__global__ void __launch_bounds__(256)
k_gru_mfma(const float* __restrict__ x, const HT* __restrict__ hprev,
           const u16* __restrict__ Wihp, const u16* __restrict__ Whhp,
           const float* __restrict__ bih, const float* __restrict__ bhh,
           OT* __restrict__ hout, int R){
  int tid = threadIdx.x;
  int wave = tid >> 6, lane = tid & 63;
  int m = lane & 15, kg = lane >> 4;
  int r0 = blockIdx.x*16;

  f32x4 agi[3][4], agh[3][4];
  #pragma unroll
  for (int g=0;g<3;g++)
    #pragma unroll
    for (int t=0;t<4;t++){ agi[g][t] = (f32x4)(0.f); agh[g][t] = (f32x4)(0.f); }

  const float* xrow = x + (size_t)(r0 + m)*GD;
  #pragma unroll
  for (int ks=0; ks<8; ks++){
    int koff = ks*32 + kg*8;
    float4 x0 = *(const float4*)&xrow[koff];
    float4 x1 = *(const float4*)&xrow[koff+4];
    bf16x8 ax;
    ax[0]=(short)f2bf(elu_(x0.x)); ax[1]=(short)f2bf(elu_(x0.y));
    ax[2]=(short)f2bf(elu_(x0.z)); ax[3]=(short)f2bf(elu_(x0.w));
    ax[4]=(short)f2bf(elu_(x1.x)); ax[5]=(short)f2bf(elu_(x1.y));
    ax[6]=(short)f2bf(elu_(x1.z)); ax[7]=(short)f2bf(elu_(x1.w));
    bf16x8 ah;
    if constexpr (sizeof(HT) == 2){
      ah = *(const bf16x8*)&hprev[(size_t)(r0 + m)*GD + koff];
    } else {
      const float* hr = (const float*)hprev + (size_t)(r0 + m)*GD + koff;
      float4 h0 = *(const float4*)hr;
      float4 h1 = *(const float4*)(hr+4);
      ah[0]=(short)f2bf(h0.x); ah[1]=(short)f2bf(h0.y); ah[2]=(short)f2bf(h0.z); ah[3]=(short)f2bf(h0.w);
      ah[4]=(short)f2bf(h1.x); ah[5]=(short)f2bf(h1.y); ah[6]=(short)f2bf(h1.z); ah[7]=(short)f2bf(h1.w);
    }
    #pragma unroll
    for (int g=0;g<3;g++){
      #pragma unroll
      for (int t=0;t<4;t++){
        int c = g*16 + wave*4 + t;
        bf16x8 bi = *(const bf16x8*)&Wihp[(size_t)((c*8 + ks)*64 + lane)*8];
        bf16x8 bh = *(const bf16x8*)&Whhp[(size_t)((c*8 + ks)*64 + lane)*8];
        agi[g][t] = __builtin_amdgcn_mfma_f32_16x16x32_bf16(ax, bi, agi[g][t], 0, 0, 0);
        agh[g][t] = __builtin_amdgcn_mfma_f32_16x16x32_bf16(ah, bh, agh[g][t], 0, 0, 0);
      }
    }
  }
  #pragma unroll
  for (int t=0;t<4;t++){
    int col = wave*64 + t*16 + m;
    float bir = bih[col],     bhr = bhh[col];
    float biz = bih[col+GD],  bhz = bhh[col+GD];
    float bin = bih[col+2*GD],bhn = bhh[col+2*GD];
    #pragma unroll
    for (int i=0;i<4;i++){
      int row = r0 + kg*4 + i;
      float rr = sigm_(agi[0][t][i] + bir + agh[0][t][i] + bhr);
      float zz = sigm_(agi[1][t][i] + biz + agh[1][t][i] + bhz);
      float nn = tanhf(agi[2][t][i] + bin + rr*(agh[2][t][i] + bhn));
      float hp = ldv(hprev, (size_t)row*GD + col);
      float o = (1.f - zz)*nn + zz*hp;
      stv(hout, (size_t)row*GD + col, fmaxf(o, 0.f));
    }
  }
}

// ---- MFMA projection ----
__global__ void __launch_bounds__(256)
k_proj_mfma(const u16* __restrict__ X, const u16* __restrict__ Wp,
            const float* __restrict__ b, u16* __restrict__ Y, int R){
  int tid = threadIdx.x;
  int wave = tid >> 6, lane = tid & 63;
  int m = lane & 15, kg = lane >> 4;
  int r0 = blockIdx.x*32;
  f32x4 acc[2][4];
  #pragma unroll
  for (int rf=0;rf<2;rf++)
    #pragma unroll
    for (int t=0;t<4;t++) acc[rf][t] = (f32x4)(0.f);
  #pragma unroll
  for (int ks=0; ks<8; ks++){
    int koff = ks*32 + kg*8;
    bf16x8 a0 = *(const bf16x8*)&X[(size_t)(r0 + m)*GD + koff];
    bf16x8 a1 = *(const bf16x8*)&X[(size_t)(r0 + 16 + m)*GD + koff];
    #pragma unroll
    for (int t=0;t<4;t++){
      int c = wave*4 + t;
      bf16x8 bv = *(const bf16x8*)&Wp[(size_t)((c*8 + ks)*64 + lane)*8];
      acc[0][t] = __builtin_amdgcn_mfma_f32_16x16x32_bf16(a0, bv, acc[0][t], 0, 0, 0);
      acc[1][t] = __builtin_amdgcn_mfma_f32_16x16x32_bf16(a1, bv, acc[1][t], 0, 0, 0);
    }
  }
  #pragma unroll
  for (int t=0;t<4;t++){
    int col = wave*64 + t*16 + m;
    float bb = b[col];
    #pragma unroll
    for (int rf=0;rf<2;rf++){
      #pragma unroll
      for (int i=0;i<4;i++){
        int row = r0 + rf*16 + kg*4 + i;
        Y[(size_t)row*GD + col] = f2bf(acc[rf][t][i] + bb);
      }
    }
  }
}

// ---- MFMA edge-transform + scatter ----
__global__ void __launch_bounds__(256)
k_et_mfma(const u16* __restrict__ P, const int* __restrict__ src, const int* __restrict__ dst,
          const float* __restrict__ ef, const float* __restrict__ Wpe1, const float* __restrict__ bpe1,
          const float* __restrict__ eexp, const float* __restrict__ sden,
          const u16* __restrict__ Wetp, const float* __restrict__ bet, float* cb, int E){
  __shared__ __align__(16) u16 she[16*264];
  __shared__ float sef[16][FE];
  __shared__ float coef[16];
  __shared__ int sd[16], ss[16];
  int tid = threadIdx.x;
  int base = blockIdx.x*16;
  for (int i = tid; i < 16*FE; i += 256){
    int n = i / FE, k = i % FE;
    sef[n][k] = ef[(size_t)(base + n)*FE + k];
  }
  if (tid < 16){
    int e = base + tid;
    int d = dst[e]; sd[tid] = d; ss[tid] = src[e]; coef[tid] = eexp[e]/sden[d];
  }
  __syncthreads();
  for (int i = tid; i < 16*GD; i += 256){
    int n = i >> 8, k = i & 255;
    float t = bf2f(P[(size_t)ss[n]*GD + k]) + bpe1[k];
    const float* wr = &Wpe1[(size_t)k*(FN+FE) + FN];
    #pragma unroll
    for (int kk=0;kk<FE;kk++) t += wr[kk]*sef[n][kk];
    she[n*264 + k] = f2bf(lrelu_(t));
  }
  __syncthreads();
  int wave = tid >> 6, lane = tid & 63;
  int m = lane & 15, kg = lane >> 4;
  f32x4 acc[4];
  #pragma unroll
  for (int t=0;t<4;t++) acc[t] = (f32x4)(0.f);
  #pragma unroll
  for (int ks=0; ks<8; ks++){
    bf16x8 a = *(const bf16x8*)&she[m*264 + ks*32 + kg*8];
    #pragma unroll
    for (int t=0;t<4;t++){
      int c = wave*4 + t;
      bf16x8 bv = *(const bf16x8*)&Wetp[(size_t)((c*8 + ks)*64 + lane)*8];
      acc[t] = __builtin_amdgcn_mfma_f32_16x16x32_bf16(a, bv, acc[t], 0, 0, 0);
    }
  }
  #pragma unroll
  for (int t=0;t<4;t++){
    int col = wave*64 + t*16 + m;
    float bb = bet[col];
    #pragma unroll
    for (int i=0;i<4;i++){
      int n = kg*4 + i;
      atomicAdd(&cb[(size_t)sd[n]*GD + col], coef[n]*(acc[t][i] + bb));
    }
  }
}

__global__ void k_scatter_seg(const u16* __restrict__ rows, const int* __restrict__ ridx,
                              const int* __restrict__ seg, const float* __restrict__ eexp,
                              const float* __restrict__ sden, float* outb, int count){
  int base = blockIdx.x*8, j = threadIdx.x;
  #pragma unroll
  for (int n=0;n<8;n++){
    int i = base + n; if (i >= count) break;
    int d = seg[i];
    float coef = eexp[i]/sden[d];
    int r = ridx ? ridx[i] : i;
    atomicAdd(&outb[(size_t)d*GD + j], coef*bf2f(rows[(size_t)r*GD + j]));
  }
}

__global__ void k_segsum(const u16* __restrict__ h, const int* __restrict__ ng, float* g, int N){
  int base = blockIdx.x*8, j = threadIdx.x;
  #pragma unroll
  for (int n=0;n<8;n++){
    int i = base + n; if (i >= N) break;
    atomicAdd(&g[(size_t)ng[i]*GD + j], bf2f(h[(size_t)i*GD + j]));
  }
}

__global__ void k_layernorm(const float* __restrict__ gb, const float* __restrict__ gamma,
                            const float* __restrict__ beta, float* __restrict__ outb){
  int r = blockIdx.x, j = threadIdx.x;
  float v = gb[(size_t)r*GD + j];
  float s1 = v, s2 = v*v;
  #pragma unroll
  for (int off=32; off; off>>=1){ s1 += __shfl_down(s1, off); s2 += __shfl_down(s2, off); }
  __shared__ float r1[4], r2[4];
  int wv = j >> 6, lane = j & 63;
  if (lane == 0){ r1[wv] = s1; r2[wv] = s2; }
  __syncthreads();
  float S1 = r1[0]+r1[1]+r1[2]+r1[3];
  float S2 = r2[0]+r2[1]+r2[2]+r2[3];
  float mu = S1/(float)GD;
  float var = fmaxf(S2/(float)GD - mu*mu, 0.f);
  outb[(size_t)r*GD + j] = (v - mu)/sqrtf(var + 1e-5f)*gamma[j] + beta[j];
}

extern "C" void kernel_launch(void* const* d_in, const int* in_sizes, int n_in,
                              void* d_out, int out_size, void* d_ws, size_t ws_size,
                              hipStream_t stream){
  const float* node_feats = (const float*)d_in[0];
  const float* edge_feats = (const float*)d_in[1];
  const int*   src        = (const int*)d_in[2];
  const int*   dst        = (const int*)d_in[3];
  const int*   node_graph = (const int*)d_in[4];
  const float* W_pn   = (const float*)d_in[5];
  const float* b_pn   = (const float*)d_in[6];
  const float* W_pe1  = (const float*)d_in[7];
  const float* b_pe1  = (const float*)d_in[8];
  const float* W_pe2  = (const float*)d_in[9];
  const float* b_pe2  = (const float*)d_in[10];
  const float* W_et   = (const float*)d_in[11];
  const float* b_et   = (const float*)d_in[12];
  const float* g0_Wih = (const float*)d_in[13];
  const float* g0_Whh = (const float*)d_in[14];
  const float* g0_bih = (const float*)d_in[15];
  const float* g0_bhh = (const float*)d_in[16];
  const float* gnn_W_pe = (const float*)d_in[17];
  const float* gnn_b_pe = (const float*)d_in[18];
  const float* gnn_W_pn = (const float*)d_in[19];
  const float* gnn_b_pn = (const float*)d_in[20];
  const float* gnn_Wih  = (const float*)d_in[21];
  const float* gnn_Whh  = (const float*)d_in[22];
  const float* gnn_bih  = (const float*)d_in[23];
  const float* gnn_bhh  = (const float*)d_in[24];
  const float* ro_W_cl = (const float*)d_in[25];
  const float* ro_b_cl = (const float*)d_in[26];
  const float* ro_W_pn = (const float*)d_in[27];
  const float* ro_b_pn = (const float*)d_in[28];
  const float* ro_Wih  = (const float*)d_in[29];
  const float* ro_Whh  = (const float*)d_in[30];
  const float* ro_bih  = (const float*)d_in[31];
  const float* ro_bhh  = (const float*)d_in[32];
  const float* ln_gamma = (const float*)d_in[33];
  const float* ln_beta  = (const float*)d_in[34];
  float* outp = (float*)d_out;

  // ---- workspace layout (bytes) ----
  char* w = (char*)d_ws;
  size_t need = 0;
  float*    cbuf  = (float*)(w + need); need += (size_t)NN*GD*4;
  float*    gbuf  = (float*)(w + need); need += (size_t)NB*GD*4;
  float*    grbuf = (float*)(w + need); need += (size_t)NB*GD*4;
  float*    logit = (float*)(w + need); need += (size_t)NE*4;
  float*    eexp  = (float*)(w + need); need += (size_t)NE*4;
  unsigned* menc  = (unsigned*)(w + need); need += (size_t)NN*4;
  float*    sden  = (float*)(w + need); need += (size_t)NN*4;
  float*    za    = (float*)(w + need); need += (size_t)NN*4;
  float*    zb    = (float*)(w + need); need += (size_t)NN*4;
  float*    zg    = (float*)(w + need); need += (size_t)NB*4;
  u16*      hbuf  = (u16*)(w + need); need += (size_t)NN*GD*2;
  u16*      htmp  = (u16*)(w + need); need += (size_t)NN*GD*2;
  u16* pGru = (u16*)(w + need); need += (size_t)10*768*GD*2;
  u16* pPn  = (u16*)(w + need); need += (size_t)4*GD*GD*2;
  u16* pEt  = (u16*)(w + need); need += (size_t)GD*GD*2;
  if (ws_size < need) return;
  u16* Pbuf   = hbuf;
  u16* hv_new = htmp;
  u16* hvtmp  = htmp;

  const size_t GW = (size_t)768*GD;
  const size_t PW = (size_t)GD*GD;

  // ---- weight packing ----
  k_pack_b<<<768, 256, 0, stream>>>(g0_Wih, pGru + 0*GW, 768, GD);
  k_pack_b<<<768, 256, 0, stream>>>(g0_Whh, pGru + 1*GW, 768, GD);
  for (int l=0;l<NL;l++){
    k_pack_b<<<768, 256, 0, stream>>>(gnn_Wih + (size_t)l*3*GD*GD, pGru + (2+2*l)*GW, 768, GD);
    k_pack_b<<<768, 256, 0, stream>>>(gnn_Whh + (size_t)l*3*GD*GD, pGru + (3+2*l)*GW, 768, GD);
    k_pack_b<<<256, 256, 0, stream>>>(gnn_W_pn + (size_t)l*GD*GD, pPn + l*PW, GD, GD);
  }
  for (int t=0;t<NT;t++){
    k_pack_b<<<768, 256, 0, stream>>>(ro_Wih + (size_t)t*3*GD*GD, pGru + (6+2*t)*GW, 768, GD);
    k_pack_b<<<768, 256, 0, stream>>>(ro_Whh + (size_t)t*3*GD*GD, pGru + (7+2*t)*GW, 768, GD);
    k_pack_b<<<256, 256, 0, stream>>>(ro_W_pn + (size_t)t*GD*GD, pPn + (2+t)*PW, GD, GD);
  }
  k_pack_b<<<256, 256, 0, stream>>>(W_et, pEt, GD, GD);

  const int ZG = 2048;
  // ---------------- GetContext ----------------
  k_node_proj<8><<<(NN+7)/8, 256, 0, stream>>>(node_feats, W_pn, FN, b_pn, 1, hv_new, NN);
  k_node_proj<8><<<(NN+7)/8, 256, 0, stream>>>(node_feats, W_pe1, FN+FE, nullptr, 0, Pbuf, NN);
  k_dot1_bf16<<<(NN+3)/4, 256, 0, stream>>>(hv_new, W_pe2, za, NN);
  k_logits_ctx2<<<(NE+3)/4, 256, 0, stream>>>(za, dst, Pbuf, src, edge_feats,
                                              W_pe1, b_pe1, W_pe2, b_pe2, logit, NE);
  k_zero<<<64, 256, 0, stream>>>((float*)menc, (size_t)2*NN);
  k_segmax<<<(NE+255)/256, 256, 0, stream>>>(logit, dst, NE, menc);
  k_expsum<<<(NE+255)/256, 256, 0, stream>>>(logit, dst, NE, menc, eexp, sden);
  k_zero<<<ZG, 256, 0, stream>>>(cbuf, (size_t)NN*GD);
  k_et_mfma<<<NE/16, 256, 0, stream>>>(Pbuf, src, dst, edge_feats, W_pe1, b_pe1,
                                       eexp, sden, pEt, b_et, cbuf, NE);
  k_gru_mfma<u16,u16><<<NN/16, 256, 0, stream>>>(cbuf, hv_new, pGru + 0*GW, pGru + 1*GW,
                                                 g0_bih, g0_bhh, hbuf, NN);

  // ---------------- GNN layers ----------------
  for (int l=0; l<NL; l++){
    k_dot2_bf16<<<(NN+3)/4, 256, 0, stream>>>(hbuf, gnn_W_pe + (size_t)l*2*GD, za, zb, NN);
    k_edge_logit<<<(NE+255)/256, 256, 0, stream>>>(za, zb, dst, src, gnn_b_pe + l, logit, NE);
    k_zero<<<64, 256, 0, stream>>>((float*)menc, (size_t)2*NN);
    k_segmax<<<(NE+255)/256, 256, 0, stream>>>(logit, dst, NE, menc);
    k_expsum<<<(NE+255)/256, 256, 0, stream>>>(logit, dst, NE, menc, eexp, sden);
    k_proj_mfma<<<NN/32, 256, 0, stream>>>(hbuf, pPn + l*PW, gnn_b_pn + (size_t)l*GD, hvtmp, NN);
    k_zero<<<ZG, 256, 0, stream>>>(cbuf, (size_t)NN*GD);
    k_scatter_seg<<<(NE+7)/8, 256, 0, stream>>>(hvtmp, src, dst, eexp, sden, cbuf, NE);
    k_gru_mfma<u16,u16><<<NN/16, 256, 0, stream>>>(cbuf, hbuf,
                                pGru + (2+2*l)*GW, pGru + (3+2*l)*GW,
                                gnn_bih + (size_t)l*3*GD, gnn_bhh + (size_t)l*3*GD, hbuf, NN);
  }

  // ---------------- Readout ----------------
  k_zero<<<256, 256, 0, stream>>>(gbuf, (size_t)NB*GD);
  k_segsum<<<(NN+7)/8, 256, 0, stream>>>(hbuf, node_graph, gbuf, NN);
  for (int t=0; t<NT; t++){
    k_dotg_relu<<<(NB+3)/4, 256, 0, stream>>>(gbuf, ro_W_cl + (size_t)t*2*GD, zg, NB);
    k_dot1_bf16<<<(NN+3)/4, 256, 0, stream>>>(hbuf, ro_W_cl + (size_t)t*2*GD + GD, za, NN);
    k_node_logit<<<(NN+255)/256, 256, 0, stream>>>(zg, node_graph, za, ro_b_cl + t, logit, NN);
    k_zero<<<64, 256, 0, stream>>>((float*)menc, (size_t)2*NN);
    k_segmax<<<(NN+255)/256, 256, 0, stream>>>(logit, node_graph, NN, menc);
    k_expsum<<<(NN+255)/256, 256, 0, stream>>>(logit, node_graph, NN, menc, eexp, sden);
    k_proj_mfma<<<NN/32, 256, 0, stream>>>(hbuf, pPn + (2+t)*PW, ro_b_pn + (size_t)t*GD, hvtmp, NN);
    k_zero<<<256, 256, 0, stream>>>(grbuf, (size_t)NB*GD);
    k_scatter_seg<<<(NN+7)/8, 256, 0, stream>>>(hvtmp, nullptr, node_graph, eexp, sden, grbuf, NN);
    k_gru_mfma<float,float><<<NB/16, 256, 0, stream>>>(grbuf, gbuf,
                                pGru + (6+2*t)*GW, pGru + (7+2*t)*GW,
                                ro_bih + (size_t)t*3*GD, ro_bhh + (size_t)t*3*GD, gbuf, NB);
  }
  k_layernorm<<<NB, 256, 0, stream>>>(gbuf, ln_gamma, ln_beta, outp);
}

// Round 7
// 2220.470 us; speedup vs baseline: 5.9410x; 1.6543x over previous
//
#include <hip/hip_runtime.h>

#define NN 100000
#define NE 400000
#define NB 4096
#define FN 78
#define FE 11
#define GD 256
#define NL 2
#define NT 2

typedef unsigned short u16;
typedef __attribute__((ext_vector_type(8))) short bf16x8;
typedef __attribute__((ext_vector_type(4))) float f32x4;

__device__ __forceinline__ float lrelu_(float x){ return x > 0.f ? x : 0.01f*x; }
__device__ __forceinline__ float elu_(float x){ return x > 0.f ? x : expf(x) - 1.f; }
__device__ __forceinline__ float sigm_(float x){ return 1.f/(1.f + expf(-x)); }

__device__ __forceinline__ float bf2f(u16 u){ return __uint_as_float(((unsigned)u) << 16); }
__device__ __forceinline__ u16 f2bf(float f){
  unsigned u = __float_as_uint(f);
  unsigned r = (u + 0x7fffu + ((u >> 16) & 1u)) >> 16;   // RNE
  return (u16)r;
}
__device__ __forceinline__ float ldv(const float* p, size_t i){ return p[i]; }
__device__ __forceinline__ float ldv(const u16* p, size_t i){ return bf2f(p[i]); }
__device__ __forceinline__ void stv(float* p, size_t i, float v){ p[i] = v; }
__device__ __forceinline__ void stv(u16* p, size_t i, float v){ p[i] = f2bf(v); }

__global__ void k_zero(float* p, size_t n){
  size_t i = (size_t)blockIdx.x*blockDim.x + threadIdx.x;
  size_t st = (size_t)gridDim.x*blockDim.x;
  for (; i < n; i += st) p[i] = 0.f;
}

// ---------------- CSR build (dst-sorted edge order) ----------------
__global__ void k_count(const int* __restrict__ dst, int* __restrict__ cnt, int E){
  int e = blockIdx.x*256 + threadIdx.x;
  if (e < E) atomicAdd(&cnt[dst[e]], 1);
}
// per-256-chunk inclusive scan; part written in place of cnt is safe (own element)
__global__ void k_scan1(const int* __restrict__ cnt, int* __restrict__ part,
                        int* __restrict__ btot, int n){
  __shared__ int sd[256];
  int i = blockIdx.x*256 + threadIdx.x;
  int v = (i < n) ? cnt[i] : 0;
  sd[threadIdx.x] = v; __syncthreads();
  for (int d=1; d<256; d<<=1){
    int t = (threadIdx.x >= d) ? sd[threadIdx.x-d] : 0;
    __syncthreads();
    sd[threadIdx.x] += t;
    __syncthreads();
  }
  if (i < n) part[i] = sd[threadIdx.x];
  if (threadIdx.x == 255) btot[blockIdx.x] = sd[255];
}
__global__ void k_scan2(const int* __restrict__ btot, int* __restrict__ boff, int nb){
  __shared__ int sd[512];
  int tid = threadIdx.x;
  int v = (tid < nb) ? btot[tid] : 0;
  sd[tid] = v; __syncthreads();
  for (int d=1; d<512; d<<=1){
    int t = (tid >= d) ? sd[tid-d] : 0;
    __syncthreads();
    sd[tid] += t;
    __syncthreads();
  }
  if (tid < nb) boff[tid] = sd[tid] - v;   // exclusive
}
__global__ void k_scan3(const int* __restrict__ part, const int* __restrict__ boff,
                        int* __restrict__ rowptr, int n){
  int i = blockIdx.x*256 + threadIdx.x;
  if (i < n) rowptr[i+1] = part[i] + boff[blockIdx.x];
  if (i == 0) rowptr[0] = 0;
}
__global__ void k_cursor(const int* __restrict__ rowptr, int* __restrict__ cursor, int n){
  int i = blockIdx.x*256 + threadIdx.x;
  if (i < n) cursor[i] = rowptr[i];
}
__global__ void k_fill(const int* __restrict__ dst, int* __restrict__ cursor,
                       int* __restrict__ order, int E){
  int e = blockIdx.x*256 + threadIdx.x;
  if (e < E){
    int pos = atomicAdd(&cursor[dst[e]], 1);
    order[pos] = e;
  }
}
// graph rowptr: node_graph is sorted; gpb[b] = lower_bound(ng, b), b in [0,B]
__global__ void k_gpb(const int* __restrict__ ng, int* __restrict__ gpb, int N, int B){
  int b = blockIdx.x*256 + threadIdx.x;
  if (b > B) return;
  int lo = 0, hi = N;
  while (lo < hi){ int mid = (lo+hi)>>1; if (ng[mid] < b) lo = mid+1; else hi = mid; }
  gpb[b] = lo;
}

// Pack W[OUT][K] f32 -> bf16 B-fragment order
__global__ void k_pack_b(const float* __restrict__ W, u16* __restrict__ Bp, int OUT, int K){
  int t = blockIdx.x*256 + threadIdx.x;
  if (t >= OUT*K) return;
  int j = t & 7;
  int l = (t >> 3) & 63;
  int rest = t >> 9;
  int nks = K >> 5;
  int ks = rest % nks, c = rest / nks;
  int col = c*16 + (l & 15);
  int k = ks*32 + (l >> 4)*8 + j;
  Bp[t] = f2bf(W[(size_t)col*K + k]);
}

// Y[r][j] = act( sum_{k<78} X[r][k]*W[j*ldw+k] + b[j] )  -> bf16 out
template<int TN>
__global__ void k_node_proj(const float* __restrict__ nf, const float* __restrict__ W, int ldw,
                            const float* __restrict__ b, int act, u16* __restrict__ outb, int N){
  __shared__ float sx[TN][FN];
  int base = blockIdx.x*TN, tid = threadIdx.x;
  for (int i = tid; i < TN*FN; i += 256){
    int n = i / FN, k = i % FN;
    int row = base + n;
    sx[n][k] = (row < N) ? nf[(size_t)row*FN + k] : 0.f;
  }
  __syncthreads();
  int j = tid;
  float acc[TN];
  #pragma unroll
  for (int n=0;n<TN;n++) acc[n]=0.f;
  for (int k=0;k<FN;k++){
    float w = W[(size_t)j*ldw + k];
    #pragma unroll
    for (int n=0;n<TN;n++) acc[n] += w*sx[n][k];
  }
  float bb = b ? b[j] : 0.f;
  #pragma unroll
  for (int n=0;n<TN;n++){
    int row = base + n;
    if (row < N){
      float v = acc[n] + bb;
      outb[(size_t)row*GD + j] = f2bf(act ? lrelu_(v) : v);
    }
  }
}

// ---- per-node dot kernels ----
__global__ void k_dot2_bf16(const u16* __restrict__ rows, const float* __restrict__ wv,
                            float* __restrict__ za, float* __restrict__ zb, int N){
  int wav = threadIdx.x >> 6, lane = threadIdx.x & 63;
  int i = blockIdx.x*4 + wav;
  if (i >= N) return;
  int c0 = lane*4;
  ushort4 r4 = *(const ushort4*)&rows[(size_t)i*GD + c0];
  float4 wa = *(const float4*)&wv[c0];
  float4 wb = *(const float4*)&wv[GD + c0];
  float v0 = bf2f(r4.x), v1 = bf2f(r4.y), v2 = bf2f(r4.z), v3 = bf2f(r4.w);
  float va = v0*wa.x + v1*wa.y + v2*wa.z + v3*wa.w;
  float vb = v0*wb.x + v1*wb.y + v2*wb.z + v3*wb.w;
  #pragma unroll
  for (int off=32; off; off>>=1){ va += __shfl_down(va, off); vb += __shfl_down(vb, off); }
  if (lane == 0){ za[i] = va; zb[i] = vb; }
}

__global__ void k_dot1_bf16(const u16* __restrict__ rows, const float* __restrict__ wv,
                            float* __restrict__ z, int N){
  int wav = threadIdx.x >> 6, lane = threadIdx.x & 63;
  int i = blockIdx.x*4 + wav;
  if (i >= N) return;
  int c0 = lane*4;
  ushort4 r4 = *(const ushort4*)&rows[(size_t)i*GD + c0];
  float4 wa = *(const float4*)&wv[c0];
  float va = bf2f(r4.x)*wa.x + bf2f(r4.y)*wa.y + bf2f(r4.z)*wa.z + bf2f(r4.w)*wa.w;
  #pragma unroll
  for (int off=32; off; off>>=1) va += __shfl_down(va, off);
  if (lane == 0) z[i] = va;
}

__global__ void k_dotg_relu(const float* __restrict__ g, const float* __restrict__ wv,
                            float* __restrict__ zg, int B){
  int wav = threadIdx.x >> 6, lane = threadIdx.x & 63;
  int i = blockIdx.x*4 + wav;
  if (i >= B) return;
  int c0 = lane*4;
  float4 gv = *(const float4*)&g[(size_t)i*GD + c0];
  float4 wa = *(const float4*)&wv[c0];
  float va = fmaxf(gv.x,0.f)*wa.x + fmaxf(gv.y,0.f)*wa.y + fmaxf(gv.z,0.f)*wa.z + fmaxf(gv.w,0.f)*wa.w;
  #pragma unroll
  for (int off=32; off; off>>=1) va += __shfl_down(va, off);
  if (lane == 0) zg[i] = va;
}

// ---- GetContext fused: per dst node, online softmax over in-edges of he1 logits,
//      accumulate wc[d] = sum_e a_e*he1_e  (c = wc@Wet^T + bet applied later via MFMA proj)
__global__ void __launch_bounds__(256)
k_ctx_fused(const u16* __restrict__ P, const float* __restrict__ za,
            const int* __restrict__ order, const int* __restrict__ rowptr,
            const int* __restrict__ src, const float* __restrict__ ef,
            const float* __restrict__ Wpe1, const float* __restrict__ bpe1,
            const float* __restrict__ Wpe2, const float* __restrict__ bpe2,
            u16* __restrict__ wc, float* __restrict__ sdeg, int N){
  int wv = threadIdx.x >> 6, lane = threadIdx.x & 63;
  int d = blockIdx.x*4 + wv;
  if (d >= N) return;
  int j0 = rowptr[d], j1 = rowptr[d+1];
  int c0 = lane*4;
  // hoisted per-lane constants
  float wb0 = Wpe2[GD+c0], wb1 = Wpe2[GD+c0+1], wb2 = Wpe2[GD+c0+2], wb3 = Wpe2[GD+c0+3];
  float bp0 = bpe1[c0], bp1 = bpe1[c0+1], bp2 = bpe1[c0+2], bp3 = bpe1[c0+3];
  float wk0[FE], wk1[FE], wk2[FE], wk3[FE];
  #pragma unroll
  for (int k=0;k<FE;k++){
    wk0[k] = Wpe1[(size_t)(c0+0)*(FN+FE) + FN + k];
    wk1[k] = Wpe1[(size_t)(c0+1)*(FN+FE) + FN + k];
    wk2[k] = Wpe1[(size_t)(c0+2)*(FN+FE) + FN + k];
    wk3[k] = Wpe1[(size_t)(c0+3)*(FN+FE) + FN + k];
  }
  float zad = za[d] + bpe2[0];
  float m = -1e30f, s = 0.f;
  float a0=0.f, a1=0.f, a2=0.f, a3=0.f;
  for (int j=j0; j<j1; j++){
    int e = order[j];
    int sn = src[e];
    ushort4 p4 = *(const ushort4*)&P[(size_t)sn*GD + c0];
    const float* efp = &ef[(size_t)e*FE];
    float efv[FE];
    #pragma unroll
    for (int k=0;k<FE;k++) efv[k] = efp[k];
    float h0 = bf2f(p4.x)+bp0, h1 = bf2f(p4.y)+bp1, h2 = bf2f(p4.z)+bp2, h3 = bf2f(p4.w)+bp3;
    #pragma unroll
    for (int k=0;k<FE;k++){
      h0 += wk0[k]*efv[k]; h1 += wk1[k]*efv[k]; h2 += wk2[k]*efv[k]; h3 += wk3[k]*efv[k];
    }
    h0 = lrelu_(h0); h1 = lrelu_(h1); h2 = lrelu_(h2); h3 = lrelu_(h3);
    float part = h0*wb0 + h1*wb1 + h2*wb2 + h3*wb3;
    #pragma unroll
    for (int off=32; off; off>>=1) part += __shfl_down(part, off);
    float l = lrelu_(part + zad);
    l = __shfl(l, 0);
    float mn = fmaxf(m, l);
    float sc = __expf(m - mn);
    float p  = __expf(l - mn);
    s = s*sc + p;
    a0 = a0*sc + p*h0; a1 = a1*sc + p*h1; a2 = a2*sc + p*h2; a3 = a3*sc + p*h3;
    m = mn;
  }
  float inv = (j1 > j0) ? 1.f/s : 0.f;
  ushort4 o;
  o.x = f2bf(a0*inv); o.y = f2bf(a1*inv); o.z = f2bf(a2*inv); o.w = f2bf(a3*inv);
  *(ushort4*)&wc[(size_t)d*GD + c0] = o;
  if (lane == 0) sdeg[d] = (j1 > j0) ? 1.f : 0.f;
}

// ---- GNN layer fused: c[d] = sum_e softmax(za[d]+zb[src]+b) * hv[src] ----
__global__ void __launch_bounds__(256)
k_gnn_fused(const u16* __restrict__ hv, const float* __restrict__ za, const float* __restrict__ zb,
            const int* __restrict__ order, const int* __restrict__ rowptr,
            const int* __restrict__ src, const float* __restrict__ bias,
            u16* __restrict__ cw, int N){
  int wv = threadIdx.x >> 6, lane = threadIdx.x & 63;
  int d = blockIdx.x*4 + wv;
  if (d >= N) return;
  int j0 = rowptr[d], j1 = rowptr[d+1];
  int c0 = lane*4;
  float zad = za[d] + bias[0];
  float m = -1e30f, s = 0.f;
  float a0=0.f, a1=0.f, a2=0.f, a3=0.f;
  for (int j=j0; j<j1; j++){
    int e = order[j];
    int sn = src[e];
    float l = lrelu_(zad + zb[sn]);
    ushort4 r4 = *(const ushort4*)&hv[(size_t)sn*GD + c0];
    float mn = fmaxf(m, l);
    float sc = __expf(m - mn);
    float p  = __expf(l - mn);
    s = s*sc + p;
    a0 = a0*sc + p*bf2f(r4.x);
    a1 = a1*sc + p*bf2f(r4.y);
    a2 = a2*sc + p*bf2f(r4.z);
    a3 = a3*sc + p*bf2f(r4.w);
    m = mn;
  }
  float inv = (j1 > j0) ? 1.f/s : 0.f;
  ushort4 o;
  o.x = f2bf(a0*inv); o.y = f2bf(a1*inv); o.z = f2bf(a2*inv); o.w = f2bf(a3*inv);
  *(ushort4*)&cw[(size_t)d*GD + c0] = o;
}

// ---- readout fused: per graph, softmax over its (contiguous) nodes, gr = sum a_i*hv[i] ----
__global__ void __launch_bounds__(256)
k_ro_fused(const u16* __restrict__ hv, const float* __restrict__ zg, const float* __restrict__ zh,
           const int* __restrict__ gpb, const float* __restrict__ bias,
           float* __restrict__ gr, int B){
  int b = blockIdx.x, tid = threadIdx.x;
  int i0 = gpb[b], i1 = gpb[b+1];
  float zgb = zg[b] + bias[0];
  __shared__ float red[256];
  float lm = -1e30f;
  for (int i = i0 + tid; i < i1; i += 256) lm = fmaxf(lm, lrelu_(zgb + zh[i]));
  red[tid] = lm; __syncthreads();
  for (int d2=128; d2; d2>>=1){ if (tid < d2) red[tid] = fmaxf(red[tid], red[tid+d2]); __syncthreads(); }
  float M = red[0]; __syncthreads();
  float ls = 0.f;
  for (int i = i0 + tid; i < i1; i += 256) ls += __expf(lrelu_(zgb + zh[i]) - M);
  red[tid] = ls; __syncthreads();
  for (int d2=128; d2; d2>>=1){ if (tid < d2) red[tid] += red[tid+d2]; __syncthreads(); }
  float S = red[0];
  float acc = 0.f;
  for (int i = i0; i < i1; i++){
    float p = __expf(lrelu_(zgb + zh[i]) - M);
    acc += p * bf2f(hv[(size_t)i*GD + tid]);
  }
  gr[(size_t)b*GD + tid] = (i1 > i0) ? acc/S : 0.f;
}

// initial g_feats = segment_sum(h) over contiguous graph segments
__global__ void k_segsum_sorted(const u16* __restrict__ h, const int* __restrict__ gpb,
                                float* __restrict__ g, int B){
  int b = blockIdx.x, tid = threadIdx.x;
  int i0 = gpb[b], i1 = gpb[b+1];
  float acc = 0.f;
  for (int i = i0; i < i1; i++) acc += bf2f(h[(size_t)i*GD + tid]);
  g[(size_t)b*GD + tid] = acc;
}

// ---- MFMA GRU: hout[r] = relu(GRU(elu(x[r] * mask), hprev[r])) ----
template<typename XT, typename HT, typename OT>
__global__ void __launch_bounds__(256)
k_gru_mfma(const XT* __restrict__ x, const HT* __restrict__ hprev,
           const u16* __restrict__ Wihp, const u16* __restrict__ Whhp,
           const float* __restrict__ bih, const float* __restrict__ bhh,
           OT* __restrict__ hout, int R, const float* __restrict__ xmask){
  int tid = threadIdx.x;
  int wave = tid >> 6, lane = tid & 63;
  int m = lane & 15, kg = lane >> 4;
  int r0 = blockIdx.x*16;

  f32x4 agi[3][4], agh[3][4];
  #pragma unroll
  for (int g=0;g<3;g++)
    #pragma unroll
    for (int t=0;t<4;t++){ agi[g][t] = (f32x4)(0.f); agh[g][t] = (f32x4)(0.f); }

  float mk = xmask ? (xmask[r0 + m] > 0.f ? 1.f : 0.f) : 1.f;
  #pragma unroll
  for (int ks=0; ks<8; ks++){
    int koff = ks*32 + kg*8;
    float xr[8];
    if constexpr (sizeof(XT) == 2){
      bf16x8 xw = *(const bf16x8*)&x[(size_t)(r0 + m)*GD + koff];
      #pragma unroll
      for (int q=0;q<8;q++) xr[q] = bf2f((u16)xw[q]);
    } else {
      const float* xp = (const float*)x + (size_t)(r0 + m)*GD + koff;
      float4 x0 = *(const float4*)xp;
      float4 x1 = *(const float4*)(xp+4);
      xr[0]=x0.x; xr[1]=x0.y; xr[2]=x0.z; xr[3]=x0.w;
      xr[4]=x1.x; xr[5]=x1.y; xr[6]=x1.z; xr[7]=x1.w;
    }
    bf16x8 ax;
    #pragma unroll
    for (int q=0;q<8;q++) ax[q] = (short)f2bf(elu_(xr[q]*mk));
    bf16x8 ah;
    if constexpr (sizeof(HT) == 2){
      ah = *(const bf16x8*)&hprev[(size_t)(r0 + m)*GD + koff];
    } else {
      const float* hr = (const float*)hprev + (size_t)(r0 + m)*GD + koff;
      float4 h0 = *(const float4*)hr;
      float4 h1 = *(const float4*)(hr+4);
      ah[0]=(short)f2bf(h0.x); ah[1]=(short)f2bf(h0.y); ah[2]=(short)f2bf(h0.z); ah[3]=(short)f2bf(h0.w);
      ah[4]=(short)f2bf(h1.x); ah[5]=(short)f2bf(h1.y); ah[6]=(short)f2bf(h1.z); ah[7]=(short)f2bf(h1.w);
    }
    #pragma unroll
    for (int g=0;g<3;g++){
      #pragma unroll
      for (int t=0;t<4;t++){
        int c = g*16 + wave*4 + t;
        bf16x8 bi = *(const bf16x8*)&Wihp[(size_t)((c*8 + ks)*64 + lane)*8];
        bf16x8 bh = *(const bf16x8*)&Whhp[(size_t)((c*8 + ks)*64 + lane)*8];
        agi[g][t] = __builtin_amdgcn_mfma_f32_16x16x32_bf16(ax, bi, agi[g][t], 0, 0, 0);
        agh[g][t] = __builtin_amdgcn_mfma_f32_16x16x32_bf16(ah, bh, agh[g][t], 0, 0, 0);
      }
    }
  }
  #pragma unroll
  for (int t=0;t<4;t++){
    int col = wave*64 + t*16 + m;
    float bir = bih[col],     bhr = bhh[col];
    float biz = bih[col+GD],  bhz = bhh[col+GD];
    float bin = bih[col+2*GD],bhn = bhh[col+2*GD];
    #pragma unroll
    for (int i=0;i<4;i++){
      int row = r0 + kg*4 + i;
      float rr = sigm_(agi[0][t][i] + bir + agh[0][t][i] + bhr);
      float zz = sigm_(agi[1][t][i] + biz + agh[1][t][i] + bhz);
      float nn = tanhf(agi[2][t][i] + bin + rr*(agh[2][t][i] + bhn));
      float hp = ldv(hprev, (size_t)row*GD + col);
      float o = (1.f - zz)*nn + zz*hp;
      stv(hout, (size_t)row*GD + col, fmaxf(o, 0.f));
    }
  }
}

// ---- MFMA projection: Y = X @ W^T + b ----
__global__ void __launch_bounds__(256)
k_proj_mfma(const u16* __restrict__ X, const u16* __restrict__ Wp,
            const float* __restrict__ b, u16* __restrict__ Y, int R){
  int tid = threadIdx.x;
  int wave = tid >> 6, lane = tid & 63;
  int m = lane & 15, kg = lane >> 4;
  int r0 = blockIdx.x*32;
  f32x4 acc[2][4];
  #pragma unroll
  for (int rf=0;rf<2;rf++)
    #pragma unroll
    for (int t=0;t<4;t++) acc[rf][t] = (f32x4)(0.f);
  #pragma unroll
  for (int ks=0; ks<8; ks++){
    int koff = ks*32 + kg*8;
    bf16x8 a0 = *(const bf16x8*)&X[(size_t)(r0 + m)*GD + koff];
    bf16x8 a1 = *(const bf16x8*)&X[(size_t)(r0 + 16 + m)*GD + koff];
    #pragma unroll
    for (int t=0;t<4;t++){
      int c = wave*4 + t;
      bf16x8 bv = *(const bf16x8*)&Wp[(size_t)((c*8 + ks)*64 + lane)*8];
      acc[0][t] = __builtin_amdgcn_mfma_f32_16x16x32_bf16(a0, bv, acc[0][t], 0, 0, 0);
      acc[1][t] = __builtin_amdgcn_mfma_f32_16x16x32_bf16(a1, bv, acc[1][t], 0, 0, 0);
    }
  }
  #pragma unroll
  for (int t=0;t<4;t++){
    int col = wave*64 + t*16 + m;
    float bb = b[col];
    #pragma unroll
    for (int rf=0;rf<2;rf++){
      #pragma unroll
      for (int i=0;i<4;i++){
        int row = r0 + rf*16 + kg*4 + i;
        Y[(size_t)row*GD + col] = f2bf(acc[rf][t][i] + bb);
      }
    }
  }
}

__global__ void k_layernorm(const float* __restrict__ gb, const float* __restrict__ gamma,
                            const float* __restrict__ beta, float* __restrict__ outb){
  int r = blockIdx.x, j = threadIdx.x;
  float v = gb[(size_t)r*GD + j];
  float s1 = v, s2 = v*v;
  #pragma unroll
  for (int off=32; off; off>>=1){ s1 += __shfl_down(s1, off); s2 += __shfl_down(s2, off); }
  __shared__ float r1[4], r2[4];
  int wv = j >> 6, lane = j & 63;
  if (lane == 0){ r1[wv] = s1; r2[wv] = s2; }
  __syncthreads();
  float S1 = r1[0]+r1[1]+r1[2]+r1[3];
  float S2 = r2[0]+r2[1]+r2[2]+r2[3];
  float mu = S1/(float)GD;
  float var = fmaxf(S2/(float)GD - mu*mu, 0.f);
  outb[(size_t)r*GD + j] = (v - mu)/sqrtf(var + 1e-5f)*gamma[j] + beta[j];
}

extern "C" void kernel_launch(void* const* d_in, const int* in_sizes, int n_in,
                              void* d_out, int out_size, void* d_ws, size_t ws_size,
                              hipStream_t stream){
  const float* node_feats = (const float*)d_in[0];
  const float* edge_feats = (const float*)d_in[1];
  const int*   src        = (const int*)d_in[2];
  const int*   dst        = (const int*)d_in[3];
  const int*   node_graph = (const int*)d_in[4];
  const float* W_pn   = (const float*)d_in[5];
  const float* b_pn   = (const float*)d_in[6];
  const float* W_pe1  = (const float*)d_in[7];
  const float* b_pe1  = (const float*)d_in[8];
  const float* W_pe2  = (const float*)d_in[9];
  const float* b_pe2  = (const float*)d_in[10];
  const float* W_et   = (const float*)d_in[11];
  const float* b_et   = (const float*)d_in[12];
  const float* g0_Wih = (const float*)d_in[13];
  const float* g0_Whh = (const float*)d_in[14];
  const float* g0_bih = (const float*)d_in[15];
  const float* g0_bhh = (const float*)d_in[16];
  const float* gnn_W_pe = (const float*)d_in[17];
  const float* gnn_b_pe = (const float*)d_in[18];
  const float* gnn_W_pn = (const float*)d_in[19];
  const float* gnn_b_pn = (const float*)d_in[20];
  const float* gnn_Wih  = (const float*)d_in[21];
  const float* gnn_Whh  = (const float*)d_in[22];
  const float* gnn_bih  = (const float*)d_in[23];
  const float* gnn_bhh  = (const float*)d_in[24];
  const float* ro_W_cl = (const float*)d_in[25];
  const float* ro_b_cl = (const float*)d_in[26];
  const float* ro_W_pn = (const float*)d_in[27];
  const float* ro_b_pn = (const float*)d_in[28];
  const float* ro_Wih  = (const float*)d_in[29];
  const float* ro_Whh  = (const float*)d_in[30];
  const float* ro_bih  = (const float*)d_in[31];
  const float* ro_bhh  = (const float*)d_in[32];
  const float* ln_gamma = (const float*)d_in[33];
  const float* ln_beta  = (const float*)d_in[34];
  float* outp = (float*)d_out;

  const int NBLK = (NN + 255)/256;   // 391 scan chunks

  // ---- workspace layout ----
  char* w = (char*)d_ws;
  size_t need = 0;
  float* gbuf  = (float*)(w + need); need += (size_t)NB*GD*4;
  float* grbuf = (float*)(w + need); need += (size_t)NB*GD*4;
  float* za    = (float*)(w + need); need += (size_t)NN*4;
  float* zb    = (float*)(w + need); need += (size_t)NN*4;
  float* zg    = (float*)(w + need); need += (size_t)NB*4;
  float* sdeg  = (float*)(w + need); need += (size_t)NN*4;
  int*   cnt    = (int*)(w + need); need += (size_t)NN*4;
  int*   rowptr = (int*)(w + need); need += (size_t)(NN+1)*4;
  int*   cursor = (int*)(w + need); need += (size_t)NN*4;
  int*   order  = (int*)(w + need); need += (size_t)NE*4;
  int*   gpb    = (int*)(w + need); need += (size_t)(NB+1)*4;
  int*   btot   = (int*)(w + need); need += (size_t)512*4;
  int*   boff   = (int*)(w + need); need += (size_t)512*4;
  u16*   hbuf = (u16*)(w + need); need += (size_t)NN*GD*2;
  u16*   htmp = (u16*)(w + need); need += (size_t)NN*GD*2;
  u16*   cwb  = (u16*)(w + need); need += (size_t)NN*GD*2;
  u16*   dbuf = (u16*)(w + need); need += (size_t)NN*GD*2;
  u16* pGru = (u16*)(w + need); need += (size_t)10*768*GD*2;
  u16* pPn  = (u16*)(w + need); need += (size_t)4*GD*GD*2;
  u16* pEt  = (u16*)(w + need); need += (size_t)GD*GD*2;
  if (ws_size < need) return;
  u16* Pbuf   = hbuf;   // P lives in hbuf until gru0 overwrites it
  u16* hv_new = htmp;

  const size_t GW = (size_t)768*GD;
  const size_t PW = (size_t)GD*GD;

  // ---- CSR build (dst-sorted edge order) + graph rowptr ----
  k_zero<<<64, 256, 0, stream>>>((float*)cnt, (size_t)NN);
  k_count<<<(NE+255)/256, 256, 0, stream>>>(dst, cnt, NE);
  k_scan1<<<NBLK, 256, 0, stream>>>(cnt, cnt, btot, NN);
  k_scan2<<<1, 512, 0, stream>>>(btot, boff, NBLK);
  k_scan3<<<NBLK, 256, 0, stream>>>(cnt, boff, rowptr, NN);
  k_cursor<<<NBLK, 256, 0, stream>>>(rowptr, cursor, NN);
  k_fill<<<(NE+255)/256, 256, 0, stream>>>(dst, cursor, order, NE);
  k_gpb<<<(NB+256)/256, 256, 0, stream>>>(node_graph, gpb, NN, NB);

  // ---- weight packing ----
  k_pack_b<<<768, 256, 0, stream>>>(g0_Wih, pGru + 0*GW, 768, GD);
  k_pack_b<<<768, 256, 0, stream>>>(g0_Whh, pGru + 1*GW, 768, GD);
  for (int l=0;l<NL;l++){
    k_pack_b<<<768, 256, 0, stream>>>(gnn_Wih + (size_t)l*3*GD*GD, pGru + (2+2*l)*GW, 768, GD);
    k_pack_b<<<768, 256, 0, stream>>>(gnn_Whh + (size_t)l*3*GD*GD, pGru + (3+2*l)*GW, 768, GD);
    k_pack_b<<<256, 256, 0, stream>>>(gnn_W_pn + (size_t)l*GD*GD, pPn + l*PW, GD, GD);
  }
  for (int t=0;t<NT;t++){
    k_pack_b<<<768, 256, 0, stream>>>(ro_Wih + (size_t)t*3*GD*GD, pGru + (6+2*t)*GW, 768, GD);
    k_pack_b<<<768, 256, 0, stream>>>(ro_Whh + (size_t)t*3*GD*GD, pGru + (7+2*t)*GW, 768, GD);
    k_pack_b<<<256, 256, 0, stream>>>(ro_W_pn + (size_t)t*GD*GD, pPn + (2+t)*PW, GD, GD);
  }
  k_pack_b<<<256, 256, 0, stream>>>(W_et, pEt, GD, GD);

  // ---------------- GetContext ----------------
  k_node_proj<8><<<(NN+7)/8, 256, 0, stream>>>(node_feats, W_pn, FN, b_pn, 1, hv_new, NN);
  k_node_proj<8><<<(NN+7)/8, 256, 0, stream>>>(node_feats, W_pe1, FN+FE, nullptr, 0, Pbuf, NN);
  k_dot1_bf16<<<(NN+3)/4, 256, 0, stream>>>(hv_new, W_pe2, za, NN);
  k_ctx_fused<<<(NN+3)/4, 256, 0, stream>>>(Pbuf, za, order, rowptr, src, edge_feats,
                                            W_pe1, b_pe1, W_pe2, b_pe2, cwb, sdeg, NN);
  k_proj_mfma<<<NN/32, 256, 0, stream>>>(cwb, pEt, b_et, dbuf, NN);
  k_gru_mfma<u16,u16,u16><<<NN/16, 256, 0, stream>>>(dbuf, hv_new, pGru + 0*GW, pGru + 1*GW,
                                                     g0_bih, g0_bhh, hbuf, NN, sdeg);

  // ---------------- GNN layers ----------------
  for (int l=0; l<NL; l++){
    k_dot2_bf16<<<(NN+3)/4, 256, 0, stream>>>(hbuf, gnn_W_pe + (size_t)l*2*GD, za, zb, NN);
    k_proj_mfma<<<NN/32, 256, 0, stream>>>(hbuf, pPn + l*PW, gnn_b_pn + (size_t)l*GD, htmp, NN);
    k_gnn_fused<<<(NN+3)/4, 256, 0, stream>>>(htmp, za, zb, order, rowptr, src,
                                              gnn_b_pe + l, cwb, NN);
    k_gru_mfma<u16,u16,u16><<<NN/16, 256, 0, stream>>>(cwb, hbuf,
                                pGru + (2+2*l)*GW, pGru + (3+2*l)*GW,
                                gnn_bih + (size_t)l*3*GD, gnn_bhh + (size_t)l*3*GD, hbuf, NN, nullptr);
  }

  // ---------------- Readout ----------------
  k_segsum_sorted<<<NB, 256, 0, stream>>>(hbuf, gpb, gbuf, NB);
  for (int t=0; t<NT; t++){
    k_dotg_relu<<<(NB+3)/4, 256, 0, stream>>>(gbuf, ro_W_cl + (size_t)t*2*GD, zg, NB);
    k_dot1_bf16<<<(NN+3)/4, 256, 0, stream>>>(hbuf, ro_W_cl + (size_t)t*2*GD + GD, za, NN);
    k_proj_mfma<<<NN/32, 256, 0, stream>>>(hbuf, pPn + (2+t)*PW, ro_b_pn + (size_t)t*GD, htmp, NN);
    k_ro_fused<<<NB, 256, 0, stream>>>(htmp, zg, za, gpb, ro_b_cl + t, grbuf, NB);
    k_gru_mfma<float,float,float><<<NB/16, 256, 0, stream>>>(grbuf, gbuf,
                                pGru + (6+2*t)*GW, pGru + (7+2*t)*GW,
                                ro_bih + (size_t)t*3*GD, ro_bhh + (size_t)t*3*GD, gbuf, NB, nullptr);
  }
  k_layernorm<<<NB, 256, 0, stream>>>(gbuf, ln_gamma, ln_beta, outp);
}